// Round 1
// 331.334 us; speedup vs baseline: 1.0219x; 1.0219x over previous
//
#include <hip/hip_runtime.h>

// ===== Problem dims =====
// B=32, L=512 -> M = 16384 rows. Inputs fp32, OUTPUTS fp32.
// ho = [emb(500) | lang(100)] pad-> K=640 ; hidden K=800 ; aux_cat K=640
// GEMM1(proj): N=512 pad (arc 100 + lab 400), fused s1/s2 epilogue
// GEMM2(aux):  N=512 pad ; GEMM3(heads): N=820 pad 896
// MFMA fp16 operands (mfma_f32_16x16x32_f16), fp32 accumulate, fp32 out.
// 3 launches: setup (grid-stride cvt/pack) -> gemm01 fused (128x8) ->
//             gemm2+arcs fused (128x8).

using f16   = _Float16;
using f16x4 = __attribute__((ext_vector_type(4))) _Float16;
using f16x8 = __attribute__((ext_vector_type(8))) _Float16;  // 8 f16 (4 VGPRs)
using f32x4 = __attribute__((ext_vector_type(4))) float;     // MFMA acc

#define M_ROWS 16384

__device__ __forceinline__ f16 f2h(float f) { return (f16)f; }  // RNE v_cvt_f16_f32
__device__ __forceinline__ f16x4 cvt4(float4 v) {
  return f16x4{ f2h(v.x), f2h(v.y), f2h(v.z), f2h(v.w) };
}

// async global->LDS, 16B per lane; LDS dest = wave-uniform base + lane*16
__device__ __forceinline__ void async16(void* lds, const void* gp) {
  __builtin_amdgcn_global_load_lds(
      (const __attribute__((address_space(1))) unsigned int*)gp,
      (__attribute__((address_space(3))) unsigned int*)lds, 16, 0, 0);
}

// ---------------------------------------------------------------------------
// Setup: grid-strided flat f16x4-quad conversion/packing. Every lane does an
// aligned float4 load + f16x4 store per iteration (no idle lanes, no
// one-row-per-block dispatch overhead).
//   range 0: hid16   [16384 x 800]  = 3,276,800 quads (flat, branch-free)
//   range 1: ho      [16384 x 640]  = 2,621,440 quads (160/row; 125 emb,
//            25 lang (dual-write to aux_cat), 10 pad (dual-write))
//   range 2: weights W_proj|W_auxp|W_heads = 327,680 quads
//   block 0 additionally packs the 1920 fp32 bias values.
// ---------------------------------------------------------------------------
__global__ __launch_bounds__(256) void setup_kernel(
    const float* __restrict__ emb, const float* __restrict__ hidden,
    const float* __restrict__ lang_table, const int* __restrict__ lang_ids,
    const float* __restrict__ W_arc, const float* __restrict__ b_arc,
    const float* __restrict__ W_lab, const float* __restrict__ b_lab,
    const float* __restrict__ W_aux, const float* __restrict__ b_aux,
    const float* __restrict__ W_upos, const float* __restrict__ b_upos,
    const float* __restrict__ W_xpos, const float* __restrict__ b_xpos,
    const float* __restrict__ W_attrs, const float* __restrict__ b_attrs,
    f16* __restrict__ ho, f16* __restrict__ aux_cat, f16* __restrict__ hid16,
    f16* __restrict__ W_proj, f16* __restrict__ W_auxp, f16* __restrict__ W_heads,
    float* __restrict__ bias_proj, float* __restrict__ bias_aux, float* __restrict__ bias_heads)
{
  const int HID_Q = 3276800;                 // 16384*200
  const int HO_Q  = 2621440;                 // 16384*160
  const int W_Q   = 327680;
  const int TOTAL = HID_Q + HO_Q + W_Q;      // 6,225,920

  for (int q = blockIdx.x * 256 + threadIdx.x; q < TOTAL; q += gridDim.x * 256) {
    if (q < HID_Q) {                         // ---- hid16 flat cvt ----
      float4 v = *(const float4*)(hidden + 4 * (size_t)q);
      *(f16x4*)(hid16 + 4 * (size_t)q) = cvt4(v);
    } else if (q < HID_Q + HO_Q) {           // ---- ho rows (+ aux lang/pad) ----
      int p = q - HID_Q;
      int row = p / 160;                     // magic-mul
      int s = p - row * 160;                 // quad in row; col = 4*s
      f16* horow = ho + (size_t)row * 640;
      if (s < 125) {                         // emb cols [0,500)
        float4 v = *(const float4*)(emb + (size_t)row * 500 + 4 * s);
        *(f16x4*)(horow + 4 * s) = cvt4(v);
      } else {                               // lang [500,600) / pad [600,640)
        f16x4 h = { (f16)0.f, (f16)0.f, (f16)0.f, (f16)0.f };
        if (s < 150) {
          const float* lrow = lang_table + (size_t)lang_ids[row >> 9] * 100;
          float4 v = *(const float4*)(lrow + (s - 125) * 4);
          h = cvt4(v);
        }
        *(f16x4*)(horow + 4 * s) = h;
        *(f16x4*)(aux_cat + (size_t)row * 640 + 4 * s) = h;
      }
    } else {                                 // ---- weight quads ----
      int w = q - (HID_Q + HO_Q);            // [0, 327680)
      const float* src = nullptr;
      f16* dst;
      if (w < 81920) {                       // W_proj [512,640] : 160 quads/row
        int n = w / 160, s = w - n * 160;
        dst = W_proj + (size_t)w * 4;
        if (s < 150 && n < 500)
          src = (n < 100 ? W_arc + (size_t)n * 600
                         : W_lab + (size_t)(n - 100) * 600) + s * 4;
      } else if (w < 184320) {               // W_auxp [512,800] : 200 quads/row
        int w2 = w - 81920;
        int n = w2 / 200;
        dst = W_auxp + (size_t)w2 * 4;
        if (n < 500) src = W_aux + (size_t)w2 * 4;
      } else {                               // W_heads [896,640] : 160 quads/row
        int w3 = w - 184320;
        int n = w3 / 160, s = w3 - n * 160;
        dst = W_heads + (size_t)w3 * 4;
        if (s < 150 && n < 820)
          src = (n < 20 ? W_upos + (size_t)n * 600
                : n < 320 ? W_xpos + (size_t)(n - 20) * 600
                          : W_attrs + (size_t)(n - 320) * 600) + s * 4;
      }
      f16x4 h = { (f16)0.f, (f16)0.f, (f16)0.f, (f16)0.f };
      if (src) h = cvt4(*(const float4*)src);
      *(f16x4*)dst = h;
    }
  }

  if (blockIdx.x == 0) {                     // ---- biases (1920 values) ----
    for (int idx = threadIdx.x; idx < 1920; idx += 256) {
      if (idx < 512) {
        float v = 0.f;
        if (idx < 100)      v = b_arc[idx];
        else if (idx < 500) v = b_lab[idx - 100];
        bias_proj[idx] = v;
      } else if (idx < 1024) {
        int i = idx - 512;
        bias_aux[i] = (i < 500) ? b_aux[i] : 0.f;
      } else {
        int i = idx - 1024; float v = 0.f;
        if (i < 20)       v = b_upos[i];
        else if (i < 320) v = b_xpos[i - 20];
        else if (i < 820) v = b_attrs[i - 320];
        bias_heads[i] = v;
      }
    }
  }
}

// ---------------------------------------------------------------------------
// Shared GEMM core: C[128,128] tile = A[M,K] * B[Npad,K]^T, 4 waves 64x64,
// BK=32, double-buffered async staging (global_load_lds w=16), 1 barrier/iter.
// ---------------------------------------------------------------------------
__device__ __forceinline__ void gemm_core(
    const f16* __restrict__ A, const f16* __restrict__ B, const int K,
    const int bm, const int bn,
    f16 (*ldsA)[128 * 32], f16 (*ldsB)[128 * 32], f32x4 (&acc)[4][4])
{
  const int tid  = threadIdx.x;
  const int lane = tid & 63;
  const int wave = tid >> 6;          // 0..3
  const int wm = wave >> 1, wn = wave & 1;
  const int m16 = lane & 15, quad = lane >> 4;

  // staging: chunk q in [0,512): row=q>>2, 8-elem group q&3; this thread's
  // lanes supply chunks q0=tid (wave-uniform LDS base wave*1024B) and q1=tid+256.
  const int q0 = tid, q1 = tid + 256;
  const f16* gA0 = A + (size_t)(bm * 128 + (q0 >> 2)) * K + (q0 & 3) * 8;
  const f16* gA1 = A + (size_t)(bm * 128 + (q1 >> 2)) * K + (q1 & 3) * 8;
  const f16* gB0 = B + (size_t)(bn * 128 + (q0 >> 2)) * K + (q0 & 3) * 8;
  const f16* gB1 = B + (size_t)(bn * 128 + (q1 >> 2)) * K + (q1 & 3) * 8;

#define STAGE(buf, k0) do {                                        \
    async16(&((uint4*)ldsA[buf])[wave * 64],       gA0 + (k0));    \
    async16(&((uint4*)ldsA[buf])[wave * 64 + 256], gA1 + (k0));    \
    async16(&((uint4*)ldsB[buf])[wave * 64],       gB0 + (k0));    \
    async16(&((uint4*)ldsB[buf])[wave * 64 + 256], gB1 + (k0));    \
  } while (0)

#define COMPUTE(buf) do {                                                        \
    f16x8 af[4], bfr[4];                                                         \
    _Pragma("unroll")                                                            \
    for (int i = 0; i < 4; ++i)                                                  \
      af[i] = *(const f16x8*)&ldsA[buf][(wm * 64 + i * 16 + m16) * 32 + quad * 8]; \
    _Pragma("unroll")                                                            \
    for (int j = 0; j < 4; ++j)                                                  \
      bfr[j] = *(const f16x8*)&ldsB[buf][(wn * 64 + j * 16 + m16) * 32 + quad * 8]; \
    _Pragma("unroll")                                                            \
    for (int i = 0; i < 4; ++i)                                                  \
      _Pragma("unroll")                                                          \
      for (int j = 0; j < 4; ++j)                                                \
        acc[i][j] = __builtin_amdgcn_mfma_f32_16x16x32_f16(af[i], bfr[j], acc[i][j], 0, 0, 0); \
  } while (0)

  STAGE(0, 0);
  __syncthreads();                    // vmcnt(0) drained -> tile 0 in LDS
  int cur = 0;
  for (int k0 = 32; k0 < K; k0 += 32) {
    STAGE(cur ^ 1, k0);               // next tile flies during compute
    COMPUTE(cur);
    __syncthreads();                  // drains lgkm (ds_reads) + vm (next tile)
    cur ^= 1;
  }
  COMPUTE(cur);                       // last tile, no trailing barrier
#undef STAGE
#undef COMPUTE
}

// ---------------------------------------------------------------------------
// Fused GEMM0+GEMM1, grid (128, 8):
//   bny<4 : proj GEMM  A=ho[16384,640]   B=W_proj  K=640, tanh epilogue;
//           cols[100,500)->out_label; bny==0 also fused s1/s2 head dots
//   bny>=4: aux  GEMM  A=hid16[16384,800] B=W_auxp K=800, tanh epilogue;
//           cols[0,500)->aux_cat (f16, ldc 640)
// ---------------------------------------------------------------------------
__global__ __launch_bounds__(256) void gemm01(
    const f16* __restrict__ ho, const f16* __restrict__ hid16,
    const f16* __restrict__ W_proj, const f16* __restrict__ W_auxp,
    const float* __restrict__ bias_proj, const float* __restrict__ bias_aux,
    float* __restrict__ out_label, const float* __restrict__ w_head,
    float* __restrict__ s1, float* __restrict__ s2, f16* __restrict__ aux_cat)
{
  __shared__ __align__(16) f16 ldsA[2][128 * 32];
  __shared__ __align__(16) f16 ldsB[2][128 * 32];
  __shared__ float s1red[2][128], s2red[2][128];

  const int tid  = threadIdx.x;
  const int lane = tid & 63;
  const int wave = tid >> 6;
  const int wm = wave >> 1, wn = wave & 1;
  const int m16 = lane & 15, quad = lane >> 4;
  const int bm  = blockIdx.x;
  const int bny = blockIdx.y;         // 0..7
  const bool is0 = (bny < 4);
  const int bn  = is0 ? bny : bny - 4;

  const f16* A = is0 ? ho : hid16;
  const f16* B = is0 ? W_proj : W_auxp;
  const float* bias = is0 ? bias_proj : bias_aux;
  const int K = is0 ? 640 : 800;

  f32x4 acc[4][4] = {};
  gemm_core(A, B, K, bm, bn, ldsA, ldsB, acc);

  // epilogue: row = bm*128 + wm*64 + i*16 + quad*4 + r ; col = bn*128 + wn*64 + j*16 + m16
  const int row0 = bm * 128 + wm * 64 + quad * 4;
  const int col0 = bn * 128 + wn * 64 + m16;

  if (is0) {
    float p1[4][4] = {}, p2[4][4] = {};
    const bool isbn0 = (bn == 0);
#pragma unroll
    for (int i = 0; i < 4; ++i) {
#pragma unroll
      for (int j = 0; j < 4; ++j) {
        const int col = col0 + j * 16;
        const float bcol = bias[col];
        float w1c = 0.f, w2c = 0.f;
        if (isbn0 && col < 100) { w1c = w_head[col]; w2c = w_head[100 + col]; }
#pragma unroll
        for (int r = 0; r < 4; ++r) {
          const int row = row0 + i * 16 + r;
          float v = tanhf(acc[i][j][r] + bcol);
          if (col >= 100 && col < 500) out_label[(size_t)row * 400 + col - 100] = v;
          p1[i][r] += v * w1c;
          p2[i][r] += v * w2c;
        }
      }
    }
    if (isbn0) {                       // block-uniform branch
#pragma unroll
      for (int d = 1; d < 16; d <<= 1) {
#pragma unroll
        for (int i = 0; i < 4; ++i)
#pragma unroll
          for (int r = 0; r < 4; ++r) {
            p1[i][r] += __shfl_xor(p1[i][r], d);
            p2[i][r] += __shfl_xor(p2[i][r], d);
          }
      }
      if (m16 == 0) {
#pragma unroll
        for (int i = 0; i < 4; ++i)
#pragma unroll
          for (int r = 0; r < 4; ++r) {
            int rl = wm * 64 + i * 16 + quad * 4 + r;
            s1red[wn][rl] = p1[i][r];
            s2red[wn][rl] = p2[i][r];
          }
      }
      __syncthreads();
      if (tid < 128)       s1[bm * 128 + tid] = s1red[0][tid] + s1red[1][tid];
      else                 s2[bm * 128 + tid - 128] = s2red[0][tid - 128] + s2red[1][tid - 128];
    }
  } else {
#pragma unroll
    for (int i = 0; i < 4; ++i)
#pragma unroll
      for (int j = 0; j < 4; ++j) {
        const int col = col0 + j * 16;
        const float bcol = bias[col];
#pragma unroll
        for (int r = 0; r < 4; ++r) {
          const int row = row0 + i * 16 + r;
          if (col < 500) aux_cat[(size_t)row * 640 + col] = f2h(tanhf(acc[i][j][r] + bcol));
        }
      }
  }
}

// ---------------------------------------------------------------------------
// Fused GEMM2 + arcs, grid (128, 8):
//   bn<7 : heads GEMM A=aux_cat[16384,640] B=W_heads K=640;
//          cols<20 upos | <320 xpos | <820 attrs (fp32)
//   bn==7: arcs rows [bm*128, bm*128+128):
//          arcs[b,i,0]=0 ; arcs[b,i,1+j] = s1[b,i] + s2[b,j] + b_head
//          (memory-bound blocks overlap the compute-bound GEMM blocks)
// ---------------------------------------------------------------------------
__global__ __launch_bounds__(256) void gemm2_arcs(
    const f16* __restrict__ aux_cat, const f16* __restrict__ W_heads,
    const float* __restrict__ bias_heads,
    const float* __restrict__ s1, const float* __restrict__ s2,
    const float* __restrict__ b_head,
    float* __restrict__ out_arcs, float* __restrict__ out_upos,
    float* __restrict__ out_xpos, float* __restrict__ out_attrs)
{
  __shared__ __align__(16) f16 ldsA[2][128 * 32];
  __shared__ __align__(16) f16 ldsB[2][128 * 32];
  __shared__ float s2s[512];

  const int bm = blockIdx.x, bn = blockIdx.y;

  if (bn == 7) {                      // ---- arcs (block-uniform branch) ----
    const int r0 = bm * 128;          // 128 rows, all in one batch b
    const int b = r0 >> 9;
    const float bh = b_head[0];
    for (int j = threadIdx.x; j < 512; j += 256) s2s[j] = s2[(b << 9) + j];
    __syncthreads();
    for (int rr = 0; rr < 128; ++rr) {
      const int row = r0 + rr;
      const float s1v = s1[row] + bh;
      float* orow = out_arcs + (size_t)row * 513;
      if (threadIdx.x == 0) orow[0] = 0.f;
#pragma unroll
      for (int j = threadIdx.x; j < 512; j += 256)
        orow[1 + j] = s1v + s2s[j];
    }
    return;
  }

  const int tid  = threadIdx.x;
  const int lane = tid & 63;
  const int wave = tid >> 6;
  const int wm = wave >> 1, wn = wave & 1;
  const int m16 = lane & 15, quad = lane >> 4;

  f32x4 acc[4][4] = {};
  gemm_core(aux_cat, W_heads, 640, bm, bn, ldsA, ldsB, acc);

  const int row0 = bm * 128 + wm * 64 + quad * 4;
  const int col0 = bn * 128 + wn * 64 + m16;
#pragma unroll
  for (int i = 0; i < 4; ++i)
#pragma unroll
    for (int j = 0; j < 4; ++j) {
      const int col = col0 + j * 16;
      const float bcol = bias_heads[col];
#pragma unroll
      for (int r = 0; r < 4; ++r) {
        const int row = row0 + i * 16 + r;
        float v = acc[i][j][r] + bcol;
        if (col < 20)        out_upos[(size_t)row * 20 + col] = v;
        else if (col < 320)  out_xpos[(size_t)row * 300 + col - 20] = v;
        else if (col < 820)  out_attrs[(size_t)row * 500 + col - 320] = v;
      }
    }
}

// ---------------------------------------------------------------------------
extern "C" void kernel_launch(void* const* d_in, const int* in_sizes, int n_in,
                              void* d_out, int out_size, void* d_ws, size_t ws_size,
                              hipStream_t stream)
{
  const float* emb      = (const float*)d_in[0];   // [32,512,500]
  const float* hidden   = (const float*)d_in[1];   // [32,512,800]
  const int*   lang_ids = (const int*)d_in[2];     // [32]
  const float* lang_tab = (const float*)d_in[3];   // [8,100]
  const float* W_arc  = (const float*)d_in[4];
  const float* b_arc  = (const float*)d_in[5];
  const float* W_lab  = (const float*)d_in[6];
  const float* b_lab  = (const float*)d_in[7];
  const float* w_head = (const float*)d_in[8];
  const float* b_head = (const float*)d_in[9];
  const float* W_aux  = (const float*)d_in[10];
  const float* b_aux  = (const float*)d_in[11];
  const float* W_upos = (const float*)d_in[12];
  const float* b_upos = (const float*)d_in[13];
  const float* W_xpos = (const float*)d_in[14];
  const float* b_xpos = (const float*)d_in[15];
  const float* W_attrs = (const float*)d_in[16];
  const float* b_attrs = (const float*)d_in[17];

  char* ws = (char*)d_ws;
  f16* ho      = (f16*)(ws + 0);                  // 16384*640*2 = 20,971,520
  f16* aux_cat = (f16*)(ws + 20971520);           // 16384*640*2
  f16* hid16   = (f16*)(ws + 41943040);           // 16384*800*2 = 26,214,400
  f16* W_proj  = (f16*)(ws + 68157440);           // 512*640*2
  f16* W_auxp  = (f16*)(ws + 68812800);           // 512*800*2
  f16* W_heads = (f16*)(ws + 69632000);           // 896*640*2
  float* bias_proj  = (float*)(ws + 70778880);    // 512*4
  float* bias_aux   = (float*)(ws + 70780928);    // 512*4
  float* bias_heads = (float*)(ws + 70782976);    // 896*4
  float* s1         = (float*)(ws + 70786560);    // 16384*4
  float* s2         = (float*)(ws + 70852096);    // 16384*4
  // total ws use: 70,917,632 bytes

  float* out       = (float*)d_out;
  float* out_arcs  = out;                 // 8,404,992
  float* out_label = out + 8404992;       // 6,553,600
  float* out_upos  = out + 14958592;      //   327,680
  float* out_xpos  = out + 15286272;      // 4,915,200
  float* out_attrs = out + 20201472;      // 8,192,000

  setup_kernel<<<2048, 256, 0, stream>>>(
      emb, hidden, lang_tab, lang_ids,
      W_arc, b_arc, W_lab, b_lab, W_aux, b_aux,
      W_upos, b_upos, W_xpos, b_xpos, W_attrs, b_attrs,
      ho, aux_cat, hid16, W_proj, W_auxp, W_heads,
      bias_proj, bias_aux, bias_heads);

  gemm01<<<dim3(128, 8), 256, 0, stream>>>(
      ho, hid16, W_proj, W_auxp, bias_proj, bias_aux,
      out_label, w_head, s1, s2, aux_cat);

  gemm2_arcs<<<dim3(128, 8), 256, 0, stream>>>(
      aux_cat, W_heads, bias_heads, s1, s2, b_head,
      out_arcs, out_upos, out_xpos, out_attrs);
}

// Round 2
// 322.248 us; speedup vs baseline: 1.0507x; 1.0282x over previous
//
#include <hip/hip_runtime.h>

// ===== Problem dims =====
// B=32, L=512 -> M = 16384 rows. Inputs fp32, OUTPUTS fp32.
// ho = [emb(500) | lang(100)] pad-> K=640 ; hidden K=800 ; aux_cat K=640
// GEMM1(proj): N=512 pad (arc 100 + lab 400), fused s1/s2 epilogue
// GEMM2(aux):  N=512 pad ; GEMM3(heads): N=820 pad 896
// MFMA fp16 operands (mfma_f32_16x16x32_f16), fp32 accumulate, fp32 out.
// K-loop: 3-buffer depth-2 prefetch, counted s_waitcnt vmcnt(4) + raw
// s_barrier (never drain vmcnt to 0 mid-loop) -- T3/T4 from the catalog.
// 3 launches: setup -> gemm01 fused (128x8) -> gemm2+arcs fused (128x8).

using f16   = _Float16;
using f16x4 = __attribute__((ext_vector_type(4))) _Float16;
using f16x8 = __attribute__((ext_vector_type(8))) _Float16;  // 8 f16 (4 VGPRs)
using f32x4 = __attribute__((ext_vector_type(4))) float;     // MFMA acc

#define M_ROWS 16384

__device__ __forceinline__ f16 f2h(float f) { return (f16)f; }  // RNE v_cvt_f16_f32
__device__ __forceinline__ f16x4 cvt4(float4 v) {
  return f16x4{ f2h(v.x), f2h(v.y), f2h(v.z), f2h(v.w) };
}

// fast tanh: 1 - 2/(2^(2x*log2e)+1); v_exp_f32 + v_rcp_f32, ~6 VALU ops.
// |err| ~1e-6 << f16 tolerance of this pipeline.
__device__ __forceinline__ float fast_tanh(float x) {
  float xc = fminf(fmaxf(x, -15.f), 15.f);
  float e  = __builtin_amdgcn_exp2f(xc * 2.885390081777927f);  // 2*log2(e)
  return 1.f - 2.f * __builtin_amdgcn_rcpf(e + 1.f);
}

// async global->LDS, 16B per lane; LDS dest = wave-uniform base + lane*16
__device__ __forceinline__ void async16(void* lds, const void* gp) {
  __builtin_amdgcn_global_load_lds(
      (const __attribute__((address_space(1))) unsigned int*)gp,
      (__attribute__((address_space(3))) unsigned int*)lds, 16, 0, 0);
}

// ---------------------------------------------------------------------------
// Setup: grid-strided flat f16x4-quad conversion/packing.
//   range 0: hid16   [16384 x 800]  = 3,276,800 quads
//   range 1: ho      [16384 x 640]  = 2,621,440 quads (dual-write lang/pad)
//   range 2: weights W_proj|W_auxp|W_heads = 327,680 quads
//   block 0 additionally packs the 1920 fp32 bias values.
// ---------------------------------------------------------------------------
__global__ __launch_bounds__(256) void setup_kernel(
    const float* __restrict__ emb, const float* __restrict__ hidden,
    const float* __restrict__ lang_table, const int* __restrict__ lang_ids,
    const float* __restrict__ W_arc, const float* __restrict__ b_arc,
    const float* __restrict__ W_lab, const float* __restrict__ b_lab,
    const float* __restrict__ W_aux, const float* __restrict__ b_aux,
    const float* __restrict__ W_upos, const float* __restrict__ b_upos,
    const float* __restrict__ W_xpos, const float* __restrict__ b_xpos,
    const float* __restrict__ W_attrs, const float* __restrict__ b_attrs,
    f16* __restrict__ ho, f16* __restrict__ aux_cat, f16* __restrict__ hid16,
    f16* __restrict__ W_proj, f16* __restrict__ W_auxp, f16* __restrict__ W_heads,
    float* __restrict__ bias_proj, float* __restrict__ bias_aux, float* __restrict__ bias_heads)
{
  const int HID_Q = 3276800;                 // 16384*200
  const int HO_Q  = 2621440;                 // 16384*160
  const int W_Q   = 327680;
  const int TOTAL = HID_Q + HO_Q + W_Q;      // 6,225,920

  for (int q = blockIdx.x * 256 + threadIdx.x; q < TOTAL; q += gridDim.x * 256) {
    if (q < HID_Q) {                         // ---- hid16 flat cvt ----
      float4 v = *(const float4*)(hidden + 4 * (size_t)q);
      *(f16x4*)(hid16 + 4 * (size_t)q) = cvt4(v);
    } else if (q < HID_Q + HO_Q) {           // ---- ho rows (+ aux lang/pad) ----
      int p = q - HID_Q;
      int row = p / 160;                     // magic-mul
      int s = p - row * 160;                 // quad in row; col = 4*s
      f16* horow = ho + (size_t)row * 640;
      if (s < 125) {                         // emb cols [0,500)
        float4 v = *(const float4*)(emb + (size_t)row * 500 + 4 * s);
        *(f16x4*)(horow + 4 * s) = cvt4(v);
      } else {                               // lang [500,600) / pad [600,640)
        f16x4 h = { (f16)0.f, (f16)0.f, (f16)0.f, (f16)0.f };
        if (s < 150) {
          const float* lrow = lang_table + (size_t)lang_ids[row >> 9] * 100;
          float4 v = *(const float4*)(lrow + (s - 125) * 4);
          h = cvt4(v);
        }
        *(f16x4*)(horow + 4 * s) = h;
        *(f16x4*)(aux_cat + (size_t)row * 640 + 4 * s) = h;
      }
    } else {                                 // ---- weight quads ----
      int w = q - (HID_Q + HO_Q);            // [0, 327680)
      const float* src = nullptr;
      f16* dst;
      if (w < 81920) {                       // W_proj [512,640] : 160 quads/row
        int n = w / 160, s = w - n * 160;
        dst = W_proj + (size_t)w * 4;
        if (s < 150 && n < 500)
          src = (n < 100 ? W_arc + (size_t)n * 600
                         : W_lab + (size_t)(n - 100) * 600) + s * 4;
      } else if (w < 184320) {               // W_auxp [512,800] : 200 quads/row
        int w2 = w - 81920;
        int n = w2 / 200;
        dst = W_auxp + (size_t)w2 * 4;
        if (n < 500) src = W_aux + (size_t)w2 * 4;
      } else {                               // W_heads [896,640] : 160 quads/row
        int w3 = w - 184320;
        int n = w3 / 160, s = w3 - n * 160;
        dst = W_heads + (size_t)w3 * 4;
        if (s < 150 && n < 820)
          src = (n < 20 ? W_upos + (size_t)n * 600
                : n < 320 ? W_xpos + (size_t)(n - 20) * 600
                          : W_attrs + (size_t)(n - 320) * 600) + s * 4;
      }
      f16x4 h = { (f16)0.f, (f16)0.f, (f16)0.f, (f16)0.f };
      if (src) h = cvt4(*(const float4*)src);
      *(f16x4*)dst = h;
    }
  }

  if (blockIdx.x == 0) {                     // ---- biases (1920 values) ----
    for (int idx = threadIdx.x; idx < 1920; idx += 256) {
      if (idx < 512) {
        float v = 0.f;
        if (idx < 100)      v = b_arc[idx];
        else if (idx < 500) v = b_lab[idx - 100];
        bias_proj[idx] = v;
      } else if (idx < 1024) {
        int i = idx - 512;
        bias_aux[i] = (i < 500) ? b_aux[i] : 0.f;
      } else {
        int i = idx - 1024; float v = 0.f;
        if (i < 20)       v = b_upos[i];
        else if (i < 320) v = b_xpos[i - 20];
        else if (i < 820) v = b_attrs[i - 320];
        bias_heads[i] = v;
      }
    }
  }
}

// ---------------------------------------------------------------------------
// GEMM core: C[128,128] tile = A[M,K] * B[Npad,K]^T, 4 waves 64x64, BK=32.
// 3-buffer depth-2 prefetch: tile t+1 and t+2 in flight across the barrier;
// s_waitcnt vmcnt(4) (counted, never 0 mid-loop) + raw s_barrier.
// Safety: buffer staged at iter t was last read at iter t-1; the stage is
// issued after the end-of-(t-1) barrier, so all waves are done reading it.
// ---------------------------------------------------------------------------
__device__ __forceinline__ void gemm_core(
    const f16* __restrict__ A, const f16* __restrict__ B, const int K,
    const int bm, const int bn,
    f16 (*ldsA)[128 * 32], f16 (*ldsB)[128 * 32], f32x4 (&acc)[4][4])
{
  const int tid  = threadIdx.x;
  const int lane = tid & 63;
  const int wave = tid >> 6;          // 0..3
  const int wm = wave >> 1, wn = wave & 1;
  const int m16 = lane & 15, quad = lane >> 4;

  // staging: chunk q in [0,512): row=q>>2, 8-elem group q&3; this thread's
  // lanes supply chunks q0=tid (wave-uniform LDS base wave*1024B) and q1=tid+256.
  const int q0 = tid, q1 = tid + 256;
  const f16* gA0 = A + (size_t)(bm * 128 + (q0 >> 2)) * K + (q0 & 3) * 8;
  const f16* gA1 = A + (size_t)(bm * 128 + (q1 >> 2)) * K + (q1 & 3) * 8;
  const f16* gB0 = B + (size_t)(bn * 128 + (q0 >> 2)) * K + (q0 & 3) * 8;
  const f16* gB1 = B + (size_t)(bn * 128 + (q1 >> 2)) * K + (q1 & 3) * 8;

#define STAGE(buf, k0) do {                                        \
    async16(&((uint4*)ldsA[buf])[wave * 64],       gA0 + (k0));    \
    async16(&((uint4*)ldsA[buf])[wave * 64 + 256], gA1 + (k0));    \
    async16(&((uint4*)ldsB[buf])[wave * 64],       gB0 + (k0));    \
    async16(&((uint4*)ldsB[buf])[wave * 64 + 256], gB1 + (k0));    \
  } while (0)

#define COMPUTE(buf) do {                                                        \
    f16x8 af[4], bfr[4];                                                         \
    _Pragma("unroll")                                                            \
    for (int i = 0; i < 4; ++i)                                                  \
      af[i] = *(const f16x8*)&ldsA[buf][(wm * 64 + i * 16 + m16) * 32 + quad * 8]; \
    _Pragma("unroll")                                                            \
    for (int j = 0; j < 4; ++j)                                                  \
      bfr[j] = *(const f16x8*)&ldsB[buf][(wn * 64 + j * 16 + m16) * 32 + quad * 8]; \
    _Pragma("unroll")                                                            \
    for (int i = 0; i < 4; ++i)                                                  \
      _Pragma("unroll")                                                          \
      for (int j = 0; j < 4; ++j)                                                \
        acc[i][j] = __builtin_amdgcn_mfma_f32_16x16x32_f16(af[i], bfr[j], acc[i][j], 0, 0, 0); \
  } while (0)

  const int NT = K >> 5;              // 20 or 25 K-tiles
  STAGE(0, 0);
  STAGE(1, 32);
  asm volatile("s_waitcnt vmcnt(4)" ::: "memory");   // tile 0 landed, tile 1 flying
  __builtin_amdgcn_s_barrier();
  __builtin_amdgcn_sched_barrier(0);

  int c0 = 0, c1 = 1, c2 = 2;         // rotating buffer indices (no modulo)
  for (int t = 0; t < NT; ++t) {
    if (t + 2 < NT) STAGE(c2, (t + 2) << 5);   // issue tile t+2
    COMPUTE(c0);                               // consume tile t
    if (t + 1 < NT) {
      if (t + 2 < NT) asm volatile("s_waitcnt vmcnt(4)" ::: "memory"); // tile t+1 in, t+2 flying
      else            asm volatile("s_waitcnt vmcnt(0)" ::: "memory"); // final drain
      __builtin_amdgcn_s_barrier();
      __builtin_amdgcn_sched_barrier(0);
      int tmp = c0; c0 = c1; c1 = c2; c2 = tmp;
    }
  }
#undef STAGE
#undef COMPUTE
}

// ---------------------------------------------------------------------------
// Fused GEMM0+GEMM1, grid (128, 8):
//   bny<4 : proj GEMM  A=ho[16384,640]   B=W_proj  K=640, tanh epilogue;
//           cols[100,500)->out_label; bny==0 also fused s1/s2 head dots
//   bny>=4: aux  GEMM  A=hid16[16384,800] B=W_auxp K=800, tanh epilogue;
//           cols[0,500)->aux_cat (f16, ldc 640)
// ---------------------------------------------------------------------------
__global__ __launch_bounds__(256) void gemm01(
    const f16* __restrict__ ho, const f16* __restrict__ hid16,
    const f16* __restrict__ W_proj, const f16* __restrict__ W_auxp,
    const float* __restrict__ bias_proj, const float* __restrict__ bias_aux,
    float* __restrict__ out_label, const float* __restrict__ w_head,
    float* __restrict__ s1, float* __restrict__ s2, f16* __restrict__ aux_cat)
{
  __shared__ __align__(16) f16 ldsA[3][128 * 32];
  __shared__ __align__(16) f16 ldsB[3][128 * 32];
  __shared__ float s1red[2][128], s2red[2][128];

  const int tid  = threadIdx.x;
  const int lane = tid & 63;
  const int wave = tid >> 6;
  const int wm = wave >> 1, wn = wave & 1;
  const int m16 = lane & 15, quad = lane >> 4;
  const int bm  = blockIdx.x;
  const int bny = blockIdx.y;         // 0..7
  const bool is0 = (bny < 4);
  const int bn  = is0 ? bny : bny - 4;

  const f16* A = is0 ? ho : hid16;
  const f16* B = is0 ? W_proj : W_auxp;
  const float* bias = is0 ? bias_proj : bias_aux;
  const int K = is0 ? 640 : 800;

  f32x4 acc[4][4] = {};
  gemm_core(A, B, K, bm, bn, ldsA, ldsB, acc);

  // epilogue: row = bm*128 + wm*64 + i*16 + quad*4 + r ; col = bn*128 + wn*64 + j*16 + m16
  const int row0 = bm * 128 + wm * 64 + quad * 4;
  const int col0 = bn * 128 + wn * 64 + m16;

  if (is0) {
    float p1[4][4] = {}, p2[4][4] = {};
    const bool isbn0 = (bn == 0);
#pragma unroll
    for (int i = 0; i < 4; ++i) {
#pragma unroll
      for (int j = 0; j < 4; ++j) {
        const int col = col0 + j * 16;
        const float bcol = bias[col];
        float w1c = 0.f, w2c = 0.f;
        if (isbn0 && col < 100) { w1c = w_head[col]; w2c = w_head[100 + col]; }
#pragma unroll
        for (int r = 0; r < 4; ++r) {
          const int row = row0 + i * 16 + r;
          float v = fast_tanh(acc[i][j][r] + bcol);
          if (col >= 100 && col < 500) out_label[(size_t)row * 400 + col - 100] = v;
          p1[i][r] += v * w1c;
          p2[i][r] += v * w2c;
        }
      }
    }
    if (isbn0) {                       // block-uniform branch
#pragma unroll
      for (int d = 1; d < 16; d <<= 1) {
#pragma unroll
        for (int i = 0; i < 4; ++i)
#pragma unroll
          for (int r = 0; r < 4; ++r) {
            p1[i][r] += __shfl_xor(p1[i][r], d);
            p2[i][r] += __shfl_xor(p2[i][r], d);
          }
      }
      if (m16 == 0) {
#pragma unroll
        for (int i = 0; i < 4; ++i)
#pragma unroll
          for (int r = 0; r < 4; ++r) {
            int rl = wm * 64 + i * 16 + quad * 4 + r;
            s1red[wn][rl] = p1[i][r];
            s2red[wn][rl] = p2[i][r];
          }
      }
      __syncthreads();
      if (tid < 128)       s1[bm * 128 + tid] = s1red[0][tid] + s1red[1][tid];
      else                 s2[bm * 128 + tid - 128] = s2red[0][tid - 128] + s2red[1][tid - 128];
    }
  } else {
#pragma unroll
    for (int i = 0; i < 4; ++i)
#pragma unroll
      for (int j = 0; j < 4; ++j) {
        const int col = col0 + j * 16;
        const float bcol = bias[col];
#pragma unroll
        for (int r = 0; r < 4; ++r) {
          const int row = row0 + i * 16 + r;
          if (col < 500) aux_cat[(size_t)row * 640 + col] = f2h(fast_tanh(acc[i][j][r] + bcol));
        }
      }
  }
}

// ---------------------------------------------------------------------------
// Fused GEMM2 + arcs, grid (128, 8):
//   bn<7 : heads GEMM A=aux_cat[16384,640] B=W_heads K=640;
//          cols<20 upos | <320 xpos | <820 attrs (fp32)
//   bn==7: arcs rows [bm*128, bm*128+128):
//          arcs[b,i,0]=0 ; arcs[b,i,1+j] = s1[b,i] + s2[b,j] + b_head
// ---------------------------------------------------------------------------
__global__ __launch_bounds__(256) void gemm2_arcs(
    const f16* __restrict__ aux_cat, const f16* __restrict__ W_heads,
    const float* __restrict__ bias_heads,
    const float* __restrict__ s1, const float* __restrict__ s2,
    const float* __restrict__ b_head,
    float* __restrict__ out_arcs, float* __restrict__ out_upos,
    float* __restrict__ out_xpos, float* __restrict__ out_attrs)
{
  __shared__ __align__(16) f16 ldsA[3][128 * 32];
  __shared__ __align__(16) f16 ldsB[3][128 * 32];
  __shared__ float s2s[512];

  const int bm = blockIdx.x, bn = blockIdx.y;

  if (bn == 7) {                      // ---- arcs (block-uniform branch) ----
    const int r0 = bm * 128;          // 128 rows, all in one batch b
    const int b = r0 >> 9;
    const float bh = b_head[0];
    for (int j = threadIdx.x; j < 512; j += 256) s2s[j] = s2[(b << 9) + j];
    __syncthreads();
    for (int rr = 0; rr < 128; ++rr) {
      const int row = r0 + rr;
      const float s1v = s1[row] + bh;
      float* orow = out_arcs + (size_t)row * 513;
      if (threadIdx.x == 0) orow[0] = 0.f;
#pragma unroll
      for (int j = threadIdx.x; j < 512; j += 256)
        orow[1 + j] = s1v + s2s[j];
    }
    return;
  }

  const int tid  = threadIdx.x;
  const int lane = tid & 63;
  const int wave = tid >> 6;
  const int wm = wave >> 1, wn = wave & 1;
  const int m16 = lane & 15, quad = lane >> 4;

  f32x4 acc[4][4] = {};
  gemm_core(aux_cat, W_heads, 640, bm, bn, ldsA, ldsB, acc);

  const int row0 = bm * 128 + wm * 64 + quad * 4;
  const int col0 = bn * 128 + wn * 64 + m16;
#pragma unroll
  for (int i = 0; i < 4; ++i)
#pragma unroll
    for (int j = 0; j < 4; ++j) {
      const int col = col0 + j * 16;
      const float bcol = bias_heads[col];
#pragma unroll
      for (int r = 0; r < 4; ++r) {
        const int row = row0 + i * 16 + r;
        float v = acc[i][j][r] + bcol;
        if (col < 20)        out_upos[(size_t)row * 20 + col] = v;
        else if (col < 320)  out_xpos[(size_t)row * 300 + col - 20] = v;
        else if (col < 820)  out_attrs[(size_t)row * 500 + col - 320] = v;
      }
    }
}

// ---------------------------------------------------------------------------
extern "C" void kernel_launch(void* const* d_in, const int* in_sizes, int n_in,
                              void* d_out, int out_size, void* d_ws, size_t ws_size,
                              hipStream_t stream)
{
  const float* emb      = (const float*)d_in[0];   // [32,512,500]
  const float* hidden   = (const float*)d_in[1];   // [32,512,800]
  const int*   lang_ids = (const int*)d_in[2];     // [32]
  const float* lang_tab = (const float*)d_in[3];   // [8,100]
  const float* W_arc  = (const float*)d_in[4];
  const float* b_arc  = (const float*)d_in[5];
  const float* W_lab  = (const float*)d_in[6];
  const float* b_lab  = (const float*)d_in[7];
  const float* w_head = (const float*)d_in[8];
  const float* b_head = (const float*)d_in[9];
  const float* W_aux  = (const float*)d_in[10];
  const float* b_aux  = (const float*)d_in[11];
  const float* W_upos = (const float*)d_in[12];
  const float* b_upos = (const float*)d_in[13];
  const float* W_xpos = (const float*)d_in[14];
  const float* b_xpos = (const float*)d_in[15];
  const float* W_attrs = (const float*)d_in[16];
  const float* b_attrs = (const float*)d_in[17];

  char* ws = (char*)d_ws;
  f16* ho      = (f16*)(ws + 0);                  // 16384*640*2 = 20,971,520
  f16* aux_cat = (f16*)(ws + 20971520);           // 16384*640*2
  f16* hid16   = (f16*)(ws + 41943040);           // 16384*800*2 = 26,214,400
  f16* W_proj  = (f16*)(ws + 68157440);           // 512*640*2
  f16* W_auxp  = (f16*)(ws + 68812800);           // 512*800*2
  f16* W_heads = (f16*)(ws + 69632000);           // 896*640*2
  float* bias_proj  = (float*)(ws + 70778880);    // 512*4
  float* bias_aux   = (float*)(ws + 70780928);    // 512*4
  float* bias_heads = (float*)(ws + 70782976);    // 896*4
  float* s1         = (float*)(ws + 70786560);    // 16384*4
  float* s2         = (float*)(ws + 70852096);    // 16384*4
  // total ws use: 70,917,632 bytes

  float* out       = (float*)d_out;
  float* out_arcs  = out;                 // 8,404,992
  float* out_label = out + 8404992;       // 6,553,600
  float* out_upos  = out + 14958592;      //   327,680
  float* out_xpos  = out + 15286272;      // 4,915,200
  float* out_attrs = out + 20201472;      // 8,192,000

  setup_kernel<<<2048, 256, 0, stream>>>(
      emb, hidden, lang_tab, lang_ids,
      W_arc, b_arc, W_lab, b_lab, W_aux, b_aux,
      W_upos, b_upos, W_xpos, b_xpos, W_attrs, b_attrs,
      ho, aux_cat, hid16, W_proj, W_auxp, W_heads,
      bias_proj, bias_aux, bias_heads);

  gemm01<<<dim3(128, 8), 256, 0, stream>>>(
      ho, hid16, W_proj, W_auxp, bias_proj, bias_aux,
      out_label, w_head, s1, s2, aux_cat);

  gemm2_arcs<<<dim3(128, 8), 256, 0, stream>>>(
      aux_cat, W_heads, bias_heads, s1, s2, b_head,
      out_arcs, out_upos, out_xpos, out_attrs);
}

// Round 3
// 298.981 us; speedup vs baseline: 1.1324x; 1.0778x over previous
//
#include <hip/hip_runtime.h>

// ===== Problem dims =====
// B=32, L=512 -> M = 16384 rows. Inputs fp32, OUTPUTS fp32.
// ho = [emb(500) | lang(100)] pad-> K=640 ; hidden K=800 pad-> 832 ; aux_cat K=640
// GEMM1(proj): N=512 pad, fused s1/s2 epilogue. GEMM2(aux): N=512 pad.
// GEMM3(heads): N=820 pad 1024, arcs fused in epilogue.
// 256x256 tile, BK=64, 8 waves (2Mx4N, wave tile 128x64), 4 phases/K-tile:
//   {stage 2 gload_lds -> ds_read frags -> barrier -> setprio MFMA x16 ->
//    counted vmcnt -> barrier}   (T2+T3+T4+T5 stack; vmcnt never 0 mid-loop)
// LDS XOR swizzle: physical slot = (k>>3) ^ (row&7); applied as pre-swizzled
// global source for global_load_lds (linear dest) + folded into ds_read base.
// 3 launches: setup -> gemm01 (64x4) -> gemm2+arcs (64x4). 1 block/CU.

using f16   = _Float16;
using f16x4 = __attribute__((ext_vector_type(4))) _Float16;
using f16x8 = __attribute__((ext_vector_type(8))) _Float16;  // 8 f16 (4 VGPRs)
using f32x4 = __attribute__((ext_vector_type(4))) float;     // MFMA acc

__device__ __forceinline__ f16 f2h(float f) { return (f16)f; }
__device__ __forceinline__ f16x4 cvt4(float4 v) {
  return f16x4{ f2h(v.x), f2h(v.y), f2h(v.z), f2h(v.w) };
}

// fast tanh: 1 - 2/(2^(2x*log2e)+1)
__device__ __forceinline__ float fast_tanh(float x) {
  float xc = fminf(fmaxf(x, -15.f), 15.f);
  float e  = __builtin_amdgcn_exp2f(xc * 2.885390081777927f);
  return 1.f - 2.f * __builtin_amdgcn_rcpf(e + 1.f);
}

// async global->LDS, 16B/lane; LDS dest = wave-uniform base + lane*16
__device__ __forceinline__ void async16(void* lds, const void* gp) {
  __builtin_amdgcn_global_load_lds(
      (const __attribute__((address_space(1))) unsigned int*)gp,
      (__attribute__((address_space(3))) unsigned int*)lds, 16, 0, 0);
}

// ---------------------------------------------------------------------------
// Setup: grid-strided flat f16x4-quad conversion/packing.
//   hid16 [16384 x 832] (hidden cols 0-799, zero-pad 800-831)
//   ho    [16384 x 640] (emb 0-499, lang 500-599 dual-write aux_cat, pad)
//   W_proj[512 x 640] | W_auxp[512 x 832] | W_heads[1024 x 640]
//   block 0: biases (512 + 512 + 1024)
// ---------------------------------------------------------------------------
__global__ __launch_bounds__(256) void setup_kernel(
    const float* __restrict__ emb, const float* __restrict__ hidden,
    const float* __restrict__ lang_table, const int* __restrict__ lang_ids,
    const float* __restrict__ W_arc, const float* __restrict__ b_arc,
    const float* __restrict__ W_lab, const float* __restrict__ b_lab,
    const float* __restrict__ W_aux, const float* __restrict__ b_aux,
    const float* __restrict__ W_upos, const float* __restrict__ b_upos,
    const float* __restrict__ W_xpos, const float* __restrict__ b_xpos,
    const float* __restrict__ W_attrs, const float* __restrict__ b_attrs,
    f16* __restrict__ ho, f16* __restrict__ aux_cat, f16* __restrict__ hid16,
    f16* __restrict__ W_proj, f16* __restrict__ W_auxp, f16* __restrict__ W_heads,
    float* __restrict__ bias_proj, float* __restrict__ bias_aux, float* __restrict__ bias_heads)
{
  const int HID_Q = 16384 * 208;             // 3,407,872
  const int HO_Q  = 16384 * 160;             // 2,621,440
  const int W_Q   = 81920 + 106496 + 163840; //   352,256
  const int TOTAL = HID_Q + HO_Q + W_Q;      // 6,381,568

  for (int q = blockIdx.x * 256 + threadIdx.x; q < TOTAL; q += gridDim.x * 256) {
    if (q < HID_Q) {                         // ---- hid16 (208 quads/row) ----
      int row = q / 208, s = q - row * 208;
      f16x4 h = { (f16)0.f, (f16)0.f, (f16)0.f, (f16)0.f };
      if (s < 200) h = cvt4(*(const float4*)(hidden + (size_t)row * 800 + 4 * s));
      *(f16x4*)(hid16 + (size_t)row * 832 + 4 * s) = h;
    } else if (q < HID_Q + HO_Q) {           // ---- ho rows (+ aux lang/pad) ----
      int p = q - HID_Q;
      int row = p / 160, s = p - row * 160;
      f16* horow = ho + (size_t)row * 640;
      if (s < 125) {
        float4 v = *(const float4*)(emb + (size_t)row * 500 + 4 * s);
        *(f16x4*)(horow + 4 * s) = cvt4(v);
      } else {
        f16x4 h = { (f16)0.f, (f16)0.f, (f16)0.f, (f16)0.f };
        if (s < 150) {
          const float* lrow = lang_table + (size_t)lang_ids[row >> 9] * 100;
          h = cvt4(*(const float4*)(lrow + (s - 125) * 4));
        }
        *(f16x4*)(horow + 4 * s) = h;
        *(f16x4*)(aux_cat + (size_t)row * 640 + 4 * s) = h;
      }
    } else {                                 // ---- weight quads ----
      int w = q - (HID_Q + HO_Q);
      const float* src = nullptr;
      f16* dst;
      if (w < 81920) {                       // W_proj [512,640] : 160 q/row
        int n = w / 160, s = w - n * 160;
        dst = W_proj + (size_t)w * 4;
        if (s < 150 && n < 500)
          src = (n < 100 ? W_arc + (size_t)n * 600
                         : W_lab + (size_t)(n - 100) * 600) + s * 4;
      } else if (w < 81920 + 106496) {       // W_auxp [512,832] : 208 q/row
        int w2 = w - 81920;
        int n = w2 / 208, s = w2 - n * 208;
        dst = W_auxp + (size_t)w2 * 4;
        if (s < 200 && n < 500) src = W_aux + (size_t)n * 800 + s * 4;
      } else {                               // W_heads [1024,640] : 160 q/row
        int w3 = w - (81920 + 106496);
        int n = w3 / 160, s = w3 - n * 160;
        dst = W_heads + (size_t)w3 * 4;
        if (s < 150 && n < 820)
          src = (n < 20 ? W_upos + (size_t)n * 600
                : n < 320 ? W_xpos + (size_t)(n - 20) * 600
                          : W_attrs + (size_t)(n - 320) * 600) + s * 4;
      }
      f16x4 h = { (f16)0.f, (f16)0.f, (f16)0.f, (f16)0.f };
      if (src) h = cvt4(*(const float4*)src);
      *(f16x4*)dst = h;
    }
  }

  if (blockIdx.x == 0) {                     // ---- biases ----
    for (int idx = threadIdx.x; idx < 2048; idx += 256) {
      if (idx < 512) {
        float v = 0.f;
        if (idx < 100)      v = b_arc[idx];
        else if (idx < 500) v = b_lab[idx - 100];
        bias_proj[idx] = v;
      } else if (idx < 1024) {
        int i = idx - 512;
        bias_aux[i] = (i < 500) ? b_aux[i] : 0.f;
      } else {
        int i = idx - 1024; float v = 0.f;
        if (i < 20)       v = b_upos[i];
        else if (i < 320) v = b_xpos[i - 20];
        else if (i < 820) v = b_attrs[i - 320];
        bias_heads[i] = v;
      }
    }
  }
}

// ---------------------------------------------------------------------------
// 256x256 BK=64 8-wave phase-split GEMM core. acc[8][4] f32x4 per thread.
// LDS layout (per matrix): [2 bufs][256 rows][64 k] f16, physical 16B slot
// within row = (k>>3) ^ (row&7)  (bank-conflict-free ds_read_b128).
// Staging: 8 gload_lds/wave/tile in order B0,B1 | B2,B3 | A0,A2 | A1,A3
// (pairs issued at phases P0..P3 for tile t+1). Waits: vmcnt(2) end-of-P0
// (retire A1,A3 of tile t) and end-of-P3 (retire B*,A0,A2 of t+1).
// ---------------------------------------------------------------------------
__device__ __forceinline__ void gemm_core256(
    const f16* __restrict__ A, const f16* __restrict__ Bm,
    const int K, const int NT, const int bm, const int bn,
    f16* __restrict__ ldsA, f16* __restrict__ ldsB, f32x4 (&acc)[8][4])
{
  const int tid  = threadIdx.x;
  const int lane = tid & 63;
  const int wave = tid >> 6;                 // 0..7
  const int wm = wave >> 2, wn = wave & 3;   // 2M x 4N
  const int m16 = lane & 15, quad = lane >> 4;

  // ---- staging addresses ----
  const int sr = lane >> 3;                  // sub-row 0..7 within wave-load
  const int ss = (lane & 7) ^ sr;            // pre-swizzled 16B slot (involution)
  const f16* gA[4]; const f16* gB[4];
#pragma unroll
  for (int i = 0; i < 4; ++i) {
    gA[i] = A  + (size_t)(bm * 256 + i * 64 + wave * 8 + sr) * K + ss * 8;
    gB[i] = Bm + (size_t)(bn * 256 + i * 64 + wave * 8 + sr) * K + ss * 8;
  }
  f16* sA = ldsA + wave * 512;               // wave-uniform; + buf*16384 + i*4096
  f16* sB = ldsB + wave * 512;

  // ---- ds_read bases (swizzle folded per-lane: slot ^= m16&7) ----
  const int aBase = (wm * 128 + m16) * 64;
  const int bBase = (wn * 64  + m16) * 64;
  const int sw0 = ((quad)     ^ (m16 & 7)) * 8;   // kk=0
  const int sw1 = ((4 | quad) ^ (m16 & 7)) * 8;   // kk=1

  f16x8 af[4], bf[4];

#define RDA(mqv, sw) { _Pragma("unroll")                                        \
  for (int ii = 0; ii < 4; ++ii)                                                \
    af[ii] = *(const f16x8*)&ldsA[buf + aBase + (mqv) * 4096 + ii * 1024 + (sw)]; }
#define RDB(sw) { _Pragma("unroll")                                             \
  for (int j = 0; j < 4; ++j)                                                   \
    bf[j] = *(const f16x8*)&ldsB[buf + bBase + j * 1024 + (sw)]; }
#define MM(mqv) { _Pragma("unroll")                                             \
  for (int ii = 0; ii < 4; ++ii) { _Pragma("unroll")                            \
    for (int j = 0; j < 4; ++j)                                                 \
      acc[(mqv) * 4 + ii][j] = __builtin_amdgcn_mfma_f32_16x16x32_f16(          \
          af[ii], bf[j], acc[(mqv) * 4 + ii][j], 0, 0, 0); } }
#define VM2 { asm volatile("s_waitcnt vmcnt(2)" ::: "memory");                  \
              __builtin_amdgcn_sched_barrier(0); }
#define VM0 { asm volatile("s_waitcnt vmcnt(0)" ::: "memory");                  \
              __builtin_amdgcn_sched_barrier(0); }
#define BAR  __builtin_amdgcn_s_barrier()
#define PRIO1 __builtin_amdgcn_s_setprio(1)
#define PRIO0 __builtin_amdgcn_s_setprio(0)

  // ---- prologue: stage tile 0, drain, publish ----
#pragma unroll
  for (int i = 0; i < 4; ++i) async16(sB + i * 4096, gB[i]);
#pragma unroll
  for (int i = 0; i < 4; ++i) async16(sA + i * 4096, gA[i]);
  VM0;
  BAR;

  for (int t = 0; t < NT; ++t) {
    const int buf = (t & 1) << 14;           // *16384
    const int nbf = ((t + 1) & 1) << 14;
    const bool st = (t + 1 < NT);
    const int k0n = (t + 1) << 6;

    // ---- P0: mq=0, kk=0 ----
    if (st) { async16(sB + nbf + 0 * 4096, gB[0] + k0n);
              async16(sB + nbf + 1 * 4096, gB[1] + k0n); }
    RDB(sw0); RDA(0, sw0);
    BAR;
    PRIO1; MM(0); PRIO0;
    if (t > 0) { if (st) VM2 else VM0 }      // retire A1,A3 of tile t
    BAR;
    // ---- P1: mq=1, kk=0 ----
    if (st) { async16(sB + nbf + 2 * 4096, gB[2] + k0n);
              async16(sB + nbf + 3 * 4096, gB[3] + k0n); }
    RDA(1, sw0);
    BAR;
    PRIO1; MM(1); PRIO0;
    BAR;
    // ---- P2: mq=0, kk=1 ----
    if (st) { async16(sA + nbf + 0 * 4096, gA[0] + k0n);
              async16(sA + nbf + 2 * 4096, gA[2] + k0n); }
    RDB(sw1); RDA(0, sw1);
    BAR;
    PRIO1; MM(0); PRIO0;
    BAR;
    // ---- P3: mq=1, kk=1 ----
    if (st) { async16(sA + nbf + 1 * 4096, gA[1] + k0n);
              async16(sA + nbf + 3 * 4096, gA[3] + k0n); }
    RDA(1, sw1);
    BAR;
    PRIO1; MM(1); PRIO0;
    if (st) VM2;                             // retire B0-3,A0,A2 of tile t+1
    BAR;
  }
#undef RDA
#undef RDB
#undef MM
#undef VM2
#undef VM0
#undef BAR
#undef PRIO1
#undef PRIO0
}

// ---------------------------------------------------------------------------
// Fused GEMM0+GEMM1, grid (64, 4), 512 threads:
//   bny<2 : proj GEMM A=ho[16384,640]   B=W_proj  K=640  NT=10, tanh;
//           cols[100,500)->out_label; bny==0: fused s1/s2 head dots
//   bny>=2: aux  GEMM A=hid16[16384,832] B=W_auxp K=832  NT=13, tanh;
//           cols[0,500)->aux_cat (f16, ldc 640)
// ---------------------------------------------------------------------------
__global__ __launch_bounds__(512, 2) void gemm01(
    const f16* __restrict__ ho, const f16* __restrict__ hid16,
    const f16* __restrict__ W_proj, const f16* __restrict__ W_auxp,
    const float* __restrict__ bias_proj, const float* __restrict__ bias_aux,
    float* __restrict__ out_label, const float* __restrict__ w_head,
    float* __restrict__ s1, float* __restrict__ s2, f16* __restrict__ aux_cat)
{
  __shared__ __align__(16) f16 ldsA[2 * 16384];
  __shared__ __align__(16) f16 ldsB[2 * 16384];
  __shared__ float s1red[2][256], s2red[2][256];

  const int tid  = threadIdx.x;
  const int lane = tid & 63;
  const int wave = tid >> 6;
  const int wm = wave >> 2, wn = wave & 3;
  const int m16 = lane & 15, quad = lane >> 4;
  const int bm  = blockIdx.x;
  const int bny = blockIdx.y;                // 0..3
  const bool is0 = (bny < 2);
  const int bn  = is0 ? bny : bny - 2;

  const f16* A = is0 ? ho : hid16;
  const f16* B = is0 ? W_proj : W_auxp;
  const float* bias = is0 ? bias_proj : bias_aux;
  const int K  = is0 ? 640 : 832;
  const int NT = is0 ? 10 : 13;

  f32x4 acc[8][4] = {};
  gemm_core256(A, B, K, NT, bm, bn, ldsA, ldsB, acc);

  // row = bm*256 + wm*128 + ai*16 + quad*4 + r ; col = bn*256 + wn*64 + j*16 + m16
  const int row0 = bm * 256 + wm * 128 + quad * 4;
  const int colT = bn * 256 + wn * 64 + m16;

  if (is0) {
    float p1[8][4] = {}, p2[8][4] = {};
    const bool haveHead = (bn == 0);
#pragma unroll
    for (int ai = 0; ai < 8; ++ai) {
#pragma unroll
      for (int j = 0; j < 4; ++j) {
        const int col = colT + j * 16;
        const float bcol = bias[col];
        float w1c = 0.f, w2c = 0.f;
        if (haveHead && col < 100) { w1c = w_head[col]; w2c = w_head[100 + col]; }
#pragma unroll
        for (int r = 0; r < 4; ++r) {
          const int row = row0 + ai * 16 + r;
          float v = fast_tanh(acc[ai][j][r] + bcol);
          if (col >= 100 && col < 500) out_label[(size_t)row * 400 + col - 100] = v;
          p1[ai][r] += v * w1c;
          p2[ai][r] += v * w2c;
        }
      }
    }
    if (haveHead) {                          // block-uniform
      if (wn < 2) {                          // only waves holding cols < 128
#pragma unroll
        for (int d = 1; d < 16; d <<= 1)
#pragma unroll
          for (int ai = 0; ai < 8; ++ai)
#pragma unroll
            for (int r = 0; r < 4; ++r) {
              p1[ai][r] += __shfl_xor(p1[ai][r], d);
              p2[ai][r] += __shfl_xor(p2[ai][r], d);
            }
        if (m16 == 0) {
#pragma unroll
          for (int ai = 0; ai < 8; ++ai)
#pragma unroll
            for (int r = 0; r < 4; ++r) {
              int rl = wm * 128 + ai * 16 + quad * 4 + r;
              s1red[wn][rl] = p1[ai][r];
              s2red[wn][rl] = p2[ai][r];
            }
        }
      }
      __syncthreads();
      if (tid < 256) s1[bm * 256 + tid] = s1red[0][tid] + s1red[1][tid];
      else { int t2 = tid - 256; s2[bm * 256 + t2] = s2red[0][t2] + s2red[1][t2]; }
    }
  } else {
#pragma unroll
    for (int ai = 0; ai < 8; ++ai)
#pragma unroll
      for (int j = 0; j < 4; ++j) {
        const int col = colT + j * 16;
        if (col < 500) {
          const float bcol = bias[col];
#pragma unroll
          for (int r = 0; r < 4; ++r) {
            const int row = row0 + ai * 16 + r;
            aux_cat[(size_t)row * 640 + col] = f2h(fast_tanh(acc[ai][j][r] + bcol));
          }
        }
      }
  }
}

// ---------------------------------------------------------------------------
// Fused GEMM2 + arcs, grid (64, 4), 512 threads:
//   heads GEMM A=aux_cat[16384,640] B=W_heads[1024,640] K=640 NT=10;
//   cols<20 upos | <320 xpos | <820 attrs (fp32; cols 820-1023 dropped).
//   Then each block writes arcs rows [bm*256 + bn*64, +64):
//   arcs[b,i,0]=0 ; arcs[b,i,1+j] = s1[b,i] + s2[b,j] + b_head  (coalesced)
// ---------------------------------------------------------------------------
__global__ __launch_bounds__(512, 2) void gemm2_arcs(
    const f16* __restrict__ aux_cat, const f16* __restrict__ W_heads,
    const float* __restrict__ bias_heads,
    const float* __restrict__ s1, const float* __restrict__ s2,
    const float* __restrict__ b_head,
    float* __restrict__ out_arcs, float* __restrict__ out_upos,
    float* __restrict__ out_xpos, float* __restrict__ out_attrs)
{
  __shared__ __align__(16) f16 ldsA[2 * 16384];
  __shared__ __align__(16) f16 ldsB[2 * 16384];

  const int tid  = threadIdx.x;
  const int lane = tid & 63;
  const int wave = tid >> 6;
  const int wm = wave >> 2, wn = wave & 3;
  const int m16 = lane & 15, quad = lane >> 4;
  const int bm = blockIdx.x, bn = blockIdx.y;

  f32x4 acc[8][4] = {};
  gemm_core256(aux_cat, W_heads, 640, 10, bm, bn, ldsA, ldsB, acc);

  const int row0 = bm * 256 + wm * 128 + quad * 4;
  const int colT = bn * 256 + wn * 64 + m16;
#pragma unroll
  for (int ai = 0; ai < 8; ++ai)
#pragma unroll
    for (int j = 0; j < 4; ++j) {
      const int col = colT + j * 16;
      const float bcol = bias_heads[col];
#pragma unroll
      for (int r = 0; r < 4; ++r) {
        const int row = row0 + ai * 16 + r;
        float v = acc[ai][j][r] + bcol;
        if (col < 20)        out_upos[(size_t)row * 20 + col] = v;
        else if (col < 320)  out_xpos[(size_t)row * 300 + col - 20] = v;
        else if (col < 820)  out_attrs[(size_t)row * 500 + col - 320] = v;
      }
    }

  // ---- arcs: 64 rows per block, 512 threads = one full row per pass ----
  const int r0 = bm * 256 + bn * 64;
  const float bh = b_head[0];
  const float s2v = s2[((r0 >> 9) << 9) + tid];
  for (int rl = 0; rl < 64; ++rl) {
    const int row = r0 + rl;
    const float s1v = s1[row] + bh;
    float* orow = out_arcs + (size_t)row * 513;
    if (tid == 0) orow[0] = 0.f;
    orow[1 + tid] = s1v + s2v;
  }
}

// ---------------------------------------------------------------------------
extern "C" void kernel_launch(void* const* d_in, const int* in_sizes, int n_in,
                              void* d_out, int out_size, void* d_ws, size_t ws_size,
                              hipStream_t stream)
{
  const float* emb      = (const float*)d_in[0];   // [32,512,500]
  const float* hidden   = (const float*)d_in[1];   // [32,512,800]
  const int*   lang_ids = (const int*)d_in[2];     // [32]
  const float* lang_tab = (const float*)d_in[3];   // [8,100]
  const float* W_arc  = (const float*)d_in[4];
  const float* b_arc  = (const float*)d_in[5];
  const float* W_lab  = (const float*)d_in[6];
  const float* b_lab  = (const float*)d_in[7];
  const float* w_head = (const float*)d_in[8];
  const float* b_head = (const float*)d_in[9];
  const float* W_aux  = (const float*)d_in[10];
  const float* b_aux  = (const float*)d_in[11];
  const float* W_upos = (const float*)d_in[12];
  const float* b_upos = (const float*)d_in[13];
  const float* W_xpos = (const float*)d_in[14];
  const float* b_xpos = (const float*)d_in[15];
  const float* W_attrs = (const float*)d_in[16];
  const float* b_attrs = (const float*)d_in[17];

  char* ws = (char*)d_ws;
  f16* ho      = (f16*)(ws + 0);                  // 16384*640*2 = 20,971,520
  f16* aux_cat = (f16*)(ws + 20971520);           // 16384*640*2 = 20,971,520
  f16* hid16   = (f16*)(ws + 41943040);           // 16384*832*2 = 27,262,976
  f16* W_proj  = (f16*)(ws + 69206016);           // 512*640*2   =    655,360
  f16* W_auxp  = (f16*)(ws + 69861376);           // 512*832*2   =    851,968
  f16* W_heads = (f16*)(ws + 70713344);           // 1024*640*2  =  1,310,720
  float* bias_proj  = (float*)(ws + 72024064);    // 512*4
  float* bias_aux   = (float*)(ws + 72026112);    // 512*4
  float* bias_heads = (float*)(ws + 72028160);    // 1024*4
  float* s1         = (float*)(ws + 72032256);    // 16384*4
  float* s2         = (float*)(ws + 72097792);    // 16384*4
  // total ws use: 72,163,328 bytes

  float* out       = (float*)d_out;
  float* out_arcs  = out;                 // 8,404,992
  float* out_label = out + 8404992;       // 6,553,600
  float* out_upos  = out + 14958592;      //   327,680
  float* out_xpos  = out + 15286272;      // 4,915,200
  float* out_attrs = out + 20201472;      // 8,192,000

  setup_kernel<<<2048, 256, 0, stream>>>(
      emb, hidden, lang_tab, lang_ids,
      W_arc, b_arc, W_lab, b_lab, W_aux, b_aux,
      W_upos, b_upos, W_xpos, b_xpos, W_attrs, b_attrs,
      ho, aux_cat, hid16, W_proj, W_auxp, W_heads,
      bias_proj, bias_aux, bias_heads);

  gemm01<<<dim3(64, 4), 512, 0, stream>>>(
      ho, hid16, W_proj, W_auxp, bias_proj, bias_aux,
      out_label, w_head, s1, s2, aux_cat);

  gemm2_arcs<<<dim3(64, 4), 512, 0, stream>>>(
      aux_cat, W_heads, bias_heads, s1, s2, b_head,
      out_arcs, out_upos, out_xpos, out_attrs);
}

// Round 4
// 283.405 us; speedup vs baseline: 1.1947x; 1.0550x over previous
//
#include <hip/hip_runtime.h>

// ===== Problem dims =====
// B=32, L=512 -> M = 16384 rows. Inputs fp32, OUTPUTS fp32.
// GEMM1(proj): A=[emb|lang] K=640 (reg-staged fp32->f16), N=512 pad, tanh,
//   fused s1/s2. GEMM1b(aux): A=hidden K=800 pad 832 (reg-staged), tanh,
//   writes aux_cat (+lang/pad cols from bny==2 epilogue).
// GEMM2(heads): A=aux_cat f16 (async16), N=820 pad 1024, arcs fused.
// 256x256 tile, BK=64, 8 waves, 4 phases/K-tile (T2+T3+T4+T5 stack).
// A-staging: issue 8 global_load_dwordx4 at P0 (tile t+1), vmcnt(0)+cvt+
// swizzled ds_write_b128 at P3 (distance-3 latency cover, T14 split).
// B-staging: global_load_lds w=16 from pre-packed f16 weights (tiny setup).
// 3 launches: setup(weights+bias, ~2us) -> gemm01 (64x4) -> gemm2+arcs (64x4).

using f16   = _Float16;
using f16x4 = __attribute__((ext_vector_type(4))) _Float16;
using f16x8 = __attribute__((ext_vector_type(8))) _Float16;  // 8 f16 (4 VGPRs)
using f32x4 = __attribute__((ext_vector_type(4))) float;     // MFMA acc

__device__ __forceinline__ f16 f2h(float f) { return (f16)f; }
__device__ __forceinline__ f16x4 cvt4(float4 v) {
  return f16x4{ f2h(v.x), f2h(v.y), f2h(v.z), f2h(v.w) };
}

// fast tanh: 1 - 2/(2^(2x*log2e)+1)
__device__ __forceinline__ float fast_tanh(float x) {
  float xc = fminf(fmaxf(x, -15.f), 15.f);
  float e  = __builtin_amdgcn_exp2f(xc * 2.885390081777927f);
  return 1.f - 2.f * __builtin_amdgcn_rcpf(e + 1.f);
}

// async global->LDS, 16B/lane; LDS dest = wave-uniform base + lane*16
__device__ __forceinline__ void async16(void* lds, const void* gp) {
  __builtin_amdgcn_global_load_lds(
      (const __attribute__((address_space(1))) unsigned int*)gp,
      (__attribute__((address_space(3))) unsigned int*)lds, 16, 0, 0);
}

// ---------------------------------------------------------------------------
// Setup (tiny): pack f16 weights + fp32 biases only.
//   W_proj[512,640] | W_auxp[512,832] | W_heads[1024,640]
// ---------------------------------------------------------------------------
__global__ __launch_bounds__(256) void setup_kernel(
    const float* __restrict__ W_arc, const float* __restrict__ b_arc,
    const float* __restrict__ W_lab, const float* __restrict__ b_lab,
    const float* __restrict__ W_aux, const float* __restrict__ b_aux,
    const float* __restrict__ W_upos, const float* __restrict__ b_upos,
    const float* __restrict__ W_xpos, const float* __restrict__ b_xpos,
    const float* __restrict__ W_attrs, const float* __restrict__ b_attrs,
    f16* __restrict__ W_proj, f16* __restrict__ W_auxp, f16* __restrict__ W_heads,
    float* __restrict__ bias_proj, float* __restrict__ bias_aux, float* __restrict__ bias_heads)
{
  const int blk = blockIdx.x, t = threadIdx.x;
  if (blk < 1376) {                          // 352,256 weight quads
    int w = blk * 256 + t;
    const float* src = nullptr;
    f16* dst;
    if (w < 81920) {                         // W_proj [512,640] : 160 q/row
      int n = w / 160, s = w - n * 160;
      dst = W_proj + (size_t)w * 4;
      if (s < 150 && n < 500)
        src = (n < 100 ? W_arc + (size_t)n * 600
                       : W_lab + (size_t)(n - 100) * 600) + s * 4;
    } else if (w < 81920 + 106496) {         // W_auxp [512,832] : 208 q/row
      int w2 = w - 81920;
      int n = w2 / 208, s = w2 - n * 208;
      dst = W_auxp + (size_t)w2 * 4;
      if (s < 200 && n < 500) src = W_aux + (size_t)n * 800 + s * 4;
    } else {                                 // W_heads [1024,640] : 160 q/row
      int w3 = w - (81920 + 106496);
      int n = w3 / 160, s = w3 - n * 160;
      dst = W_heads + (size_t)w3 * 4;
      if (s < 150 && n < 820)
        src = (n < 20 ? W_upos + (size_t)n * 600
              : n < 320 ? W_xpos + (size_t)(n - 20) * 600
                        : W_attrs + (size_t)(n - 320) * 600) + s * 4;
    }
    f16x4 h = { (f16)0.f, (f16)0.f, (f16)0.f, (f16)0.f };
    if (src) h = cvt4(*(const float4*)src);
    *(f16x4*)dst = h;
    return;
  }
  for (int idx = t; idx < 2048; idx += 256) {      // ---- biases ----
    if (idx < 512) {
      float v = 0.f;
      if (idx < 100)      v = b_arc[idx];
      else if (idx < 500) v = b_lab[idx - 100];
      bias_proj[idx] = v;
    } else if (idx < 1024) {
      int i = idx - 512;
      bias_aux[i] = (i < 500) ? b_aux[i] : 0.f;
    } else {
      int i = idx - 1024; float v = 0.f;
      if (i < 20)       v = b_upos[i];
      else if (i < 320) v = b_xpos[i - 20];
      else if (i < 820) v = b_attrs[i - 320];
      bias_heads[i] = v;
    }
  }
}

// ---------------------------------------------------------------------------
// Fused GEMM0+GEMM1, grid (64, 4), 512 threads. A reg-staged from fp32.
//   bny<2 : proj A=[emb|lang|pad] K=640 NT=10; cols[100,500)->out_label;
//           bny==0: fused s1/s2 head dots
//   bny>=2: aux  A=hidden pad     K=832 NT=13; cols[0,500)->aux_cat;
//           bny==2 also writes aux_cat lang/pad cols [500,640)
// ---------------------------------------------------------------------------
__global__ __launch_bounds__(512, 2) void gemm01(
    const float* __restrict__ emb, const float* __restrict__ hidden,
    const float* __restrict__ lang_table, const int* __restrict__ lang_ids,
    const f16* __restrict__ W_proj, const f16* __restrict__ W_auxp,
    const float* __restrict__ bias_proj, const float* __restrict__ bias_aux,
    float* __restrict__ out_label, const float* __restrict__ w_head,
    float* __restrict__ s1, float* __restrict__ s2, f16* __restrict__ aux_cat)
{
  __shared__ __align__(16) f16 ldsA[2 * 16384];
  __shared__ __align__(16) f16 ldsB[2 * 16384];
  __shared__ float s1red[2][256], s2red[2][256];

  const int tid  = threadIdx.x;
  const int lane = tid & 63;
  const int wave = tid >> 6;                 // 0..7
  const int wm = wave >> 2, wn = wave & 3;   // 2M x 4N
  const int m16 = lane & 15, quad = lane >> 4;
  const int bm  = blockIdx.x;
  const int bny = blockIdx.y;                // 0..3
  const bool is0 = (bny < 2);
  const int bn  = is0 ? bny : bny - 2;
  const int K   = is0 ? 640 : 832;
  const int NT  = is0 ? 10 : 13;

  // ---- B staging (async16, pre-swizzled source) ----
  const int sr = lane >> 3;
  const int ssB = (lane & 7) ^ sr;
  const f16* Bmat = is0 ? W_proj : W_auxp;
  const f16* gB[4];
#pragma unroll
  for (int i = 0; i < 4; ++i)
    gB[i] = Bmat + (size_t)(bn * 256 + i * 64 + wave * 8 + sr) * K + ssB * 8;
  f16* sB = ldsB + wave * 512;

  // ---- A reg-staging: lane owns 4 chunks (rows wave*32+i*8+(lane>>3),
  //      slot ssA=lane&7); lang row is block-uniform (batch = bm>>1). ----
  const int ssA = lane & 7;
  const float* lrow = lang_table + (size_t)lang_ids[bm >> 1] * 100;
  const float* srcA[4];
  int dstA[4];
#pragma unroll
  for (int i = 0; i < 4; ++i) {
    const int rowA = wave * 32 + i * 8 + (lane >> 3);
    const int grow = bm * 256 + rowA;
    srcA[i] = is0 ? emb + (size_t)grow * 500 : hidden + (size_t)grow * 800;
    dstA[i] = rowA * 64 + ((ssA ^ (rowA & 7)) * 8);
  }
  float4 va[4], vb[4];

  // ---- ds_read bases ----
  const int aBase = (wm * 128 + m16) * 64;
  const int bBase = (wn * 64  + m16) * 64;
  const int sw0 = ((quad)     ^ (m16 & 7)) * 8;
  const int sw1 = ((4 | quad) ^ (m16 & 7)) * 8;

  f32x4 acc[8][4] = {};
  f16x8 af[4], bf[4];

#define ASTAGE(tt) do { const int k0b = (tt) * 64 + ssA * 8;                    \
    _Pragma("unroll")                                                           \
    for (int i2 = 0; i2 < 4; ++i2) {                                            \
      float4 x0 = {0.f,0.f,0.f,0.f}, x1 = {0.f,0.f,0.f,0.f};                    \
      if (is0) {                                                                \
        if (k0b < 500) { x0 = *(const float4*)(srcA[i2] + k0b);                 \
          x1 = (k0b + 4 < 500) ? *(const float4*)(srcA[i2] + k0b + 4)           \
                               : *(const float4*)(lrow); }                      \
        else if (k0b < 600) { x0 = *(const float4*)(lrow + k0b - 500);          \
                              x1 = *(const float4*)(lrow + k0b - 496); }        \
      } else if (k0b < 800) { x0 = *(const float4*)(srcA[i2] + k0b);            \
                              x1 = *(const float4*)(srcA[i2] + k0b + 4); }      \
      va[i2] = x0; vb[i2] = x1; } } while (0)

#define AWRITE(nbf) do { _Pragma("unroll")                                      \
    for (int i2 = 0; i2 < 4; ++i2) {                                            \
      f16x8 hw = { f2h(va[i2].x), f2h(va[i2].y), f2h(va[i2].z), f2h(va[i2].w),  \
                   f2h(vb[i2].x), f2h(vb[i2].y), f2h(vb[i2].z), f2h(vb[i2].w) };\
      *(f16x8*)&ldsA[(nbf) + dstA[i2]] = hw; } } while (0)

#define RDA(mqv, sw) { _Pragma("unroll")                                        \
  for (int ii = 0; ii < 4; ++ii)                                                \
    af[ii] = *(const f16x8*)&ldsA[buf + aBase + (mqv) * 4096 + ii * 1024 + (sw)]; }
#define RDB(sw) { _Pragma("unroll")                                             \
  for (int j = 0; j < 4; ++j)                                                   \
    bf[j] = *(const f16x8*)&ldsB[buf + bBase + j * 1024 + (sw)]; }
#define MM(mqv) { _Pragma("unroll")                                             \
  for (int ii = 0; ii < 4; ++ii) { _Pragma("unroll")                            \
    for (int j = 0; j < 4; ++j)                                                 \
      acc[(mqv) * 4 + ii][j] = __builtin_amdgcn_mfma_f32_16x16x32_f16(          \
          af[ii], bf[j], acc[(mqv) * 4 + ii][j], 0, 0, 0); } }
#define VM0 { asm volatile("s_waitcnt vmcnt(0)" ::: "memory");                  \
              __builtin_amdgcn_sched_barrier(0); }
#define LGK0 { asm volatile("s_waitcnt lgkmcnt(0)" ::: "memory");               \
               __builtin_amdgcn_sched_barrier(0); }
#define BAR  __builtin_amdgcn_s_barrier()
#define PRIO1 __builtin_amdgcn_s_setprio(1)
#define PRIO0 __builtin_amdgcn_s_setprio(0)

  // ---- prologue: tile 0 ----
#pragma unroll
  for (int i = 0; i < 4; ++i) async16(sB + i * 4096, gB[i]);
  ASTAGE(0);
  VM0;
  AWRITE(0);
  LGK0;
  BAR;

  for (int t = 0; t < NT; ++t) {
    const int buf = (t & 1) << 14;
    const int nbf = ((t + 1) & 1) << 14;
    const bool st = (t + 1 < NT);
    const int k0n = (t + 1) << 6;

    // P0: issue ALL staging for t+1 (4 async16 B + 8 glb A), compute mq0/kk0
    if (st) {
      async16(sB + nbf + 0 * 4096, gB[0] + k0n);
      async16(sB + nbf + 1 * 4096, gB[1] + k0n);
      async16(sB + nbf + 2 * 4096, gB[2] + k0n);
      async16(sB + nbf + 3 * 4096, gB[3] + k0n);
      ASTAGE(t + 1);
    }
    RDB(sw0); RDA(0, sw0);
    BAR;
    PRIO1; MM(0); PRIO0;
    BAR;
    // P1
    RDA(1, sw0);
    BAR;
    PRIO1; MM(1); PRIO0;
    BAR;
    // P2
    RDB(sw1); RDA(0, sw1);
    BAR;
    PRIO1; MM(0); PRIO0;
    BAR;
    // P3: land A (distance-3 vmcnt(0)), swizzled ds_write, publish
    RDA(1, sw1);
    if (st) { VM0; AWRITE(nbf); }
    LGK0;
    BAR;
    PRIO1; MM(1); PRIO0;
    BAR;
  }
#undef ASTAGE
#undef AWRITE
#undef RDA
#undef RDB
#undef MM
#undef VM0
#undef LGK0
#undef BAR
#undef PRIO1
#undef PRIO0

  // ---- epilogue ----
  const int row0 = bm * 256 + wm * 128 + quad * 4;
  const int colT = bn * 256 + wn * 64 + m16;

  if (is0) {
    const float* bias = bias_proj;
    float p1[8][4] = {}, p2[8][4] = {};
    const bool haveHead = (bn == 0);
#pragma unroll
    for (int ai = 0; ai < 8; ++ai) {
#pragma unroll
      for (int j = 0; j < 4; ++j) {
        const int col = colT + j * 16;
        const float bcol = bias[col];
        float w1c = 0.f, w2c = 0.f;
        if (haveHead && col < 100) { w1c = w_head[col]; w2c = w_head[100 + col]; }
#pragma unroll
        for (int r = 0; r < 4; ++r) {
          const int row = row0 + ai * 16 + r;
          float v = fast_tanh(acc[ai][j][r] + bcol);
          if (col >= 100 && col < 500) out_label[(size_t)row * 400 + col - 100] = v;
          p1[ai][r] += v * w1c;
          p2[ai][r] += v * w2c;
        }
      }
    }
    if (haveHead) {
      if (wn < 2) {
#pragma unroll
        for (int d = 1; d < 16; d <<= 1)
#pragma unroll
          for (int ai = 0; ai < 8; ++ai)
#pragma unroll
            for (int r = 0; r < 4; ++r) {
              p1[ai][r] += __shfl_xor(p1[ai][r], d);
              p2[ai][r] += __shfl_xor(p2[ai][r], d);
            }
        if (m16 == 0) {
#pragma unroll
          for (int ai = 0; ai < 8; ++ai)
#pragma unroll
            for (int r = 0; r < 4; ++r) {
              int rl = wm * 128 + ai * 16 + quad * 4 + r;
              s1red[wn][rl] = p1[ai][r];
              s2red[wn][rl] = p2[ai][r];
            }
        }
      }
      __syncthreads();
      if (tid < 256) s1[bm * 256 + tid] = s1red[0][tid] + s1red[1][tid];
      else { int t2 = tid - 256; s2[bm * 256 + t2] = s2red[0][t2] + s2red[1][t2]; }
    }
  } else {
    const float* bias = bias_aux;
#pragma unroll
    for (int ai = 0; ai < 8; ++ai)
#pragma unroll
      for (int j = 0; j < 4; ++j) {
        const int col = colT + j * 16;
        if (col < 500) {
          const float bcol = bias[col];
#pragma unroll
          for (int r = 0; r < 4; ++r) {
            const int row = row0 + ai * 16 + r;
            aux_cat[(size_t)row * 640 + col] = f2h(fast_tanh(acc[ai][j][r] + bcol));
          }
        }
      }
    if (bn == 0) {                           // bny==2: lang/pad cols [500,640)
      for (int idx = tid; idx < 256 * 35; idx += 512) {
        int rr = idx / 35, qq = idx - rr * 35;
        int col = 500 + 4 * qq;
        f16x4 h = { (f16)0.f, (f16)0.f, (f16)0.f, (f16)0.f };
        if (col < 600) h = cvt4(*(const float4*)(lrow + col - 500));
        *(f16x4*)(aux_cat + (size_t)(bm * 256 + rr) * 640 + col) = h;
      }
    }
  }
}

// ---------------------------------------------------------------------------
// Fused GEMM2 + arcs, grid (64, 4), 512 threads (unchanged from R3):
//   heads GEMM A=aux_cat[16384,640] B=W_heads[1024,640] K=640 NT=10;
//   cols<20 upos | <320 xpos | <820 attrs. Then arcs rows [bm*256+bn*64,+64).
// ---------------------------------------------------------------------------
__global__ __launch_bounds__(512, 2) void gemm2_arcs(
    const f16* __restrict__ aux_cat, const f16* __restrict__ W_heads,
    const float* __restrict__ bias_heads,
    const float* __restrict__ s1, const float* __restrict__ s2,
    const float* __restrict__ b_head,
    float* __restrict__ out_arcs, float* __restrict__ out_upos,
    float* __restrict__ out_xpos, float* __restrict__ out_attrs)
{
  __shared__ __align__(16) f16 ldsA[2 * 16384];
  __shared__ __align__(16) f16 ldsB[2 * 16384];

  const int tid  = threadIdx.x;
  const int lane = tid & 63;
  const int wave = tid >> 6;
  const int wm = wave >> 2, wn = wave & 3;
  const int m16 = lane & 15, quad = lane >> 4;
  const int bm = blockIdx.x, bn = blockIdx.y;
  const int K = 640, NT = 10;

  const int sr = lane >> 3;
  const int ss = (lane & 7) ^ sr;
  const f16* gA[4]; const f16* gB[4];
#pragma unroll
  for (int i = 0; i < 4; ++i) {
    gA[i] = aux_cat + (size_t)(bm * 256 + i * 64 + wave * 8 + sr) * K + ss * 8;
    gB[i] = W_heads + (size_t)(bn * 256 + i * 64 + wave * 8 + sr) * K + ss * 8;
  }
  f16* sA = ldsA + wave * 512;
  f16* sB = ldsB + wave * 512;

  const int aBase = (wm * 128 + m16) * 64;
  const int bBase = (wn * 64  + m16) * 64;
  const int sw0 = ((quad)     ^ (m16 & 7)) * 8;
  const int sw1 = ((4 | quad) ^ (m16 & 7)) * 8;

  f32x4 acc[8][4] = {};
  f16x8 af[4], bf[4];

#define RDA(mqv, sw) { _Pragma("unroll")                                        \
  for (int ii = 0; ii < 4; ++ii)                                                \
    af[ii] = *(const f16x8*)&ldsA[buf + aBase + (mqv) * 4096 + ii * 1024 + (sw)]; }
#define RDB(sw) { _Pragma("unroll")                                             \
  for (int j = 0; j < 4; ++j)                                                   \
    bf[j] = *(const f16x8*)&ldsB[buf + bBase + j * 1024 + (sw)]; }
#define MM(mqv) { _Pragma("unroll")                                             \
  for (int ii = 0; ii < 4; ++ii) { _Pragma("unroll")                            \
    for (int j = 0; j < 4; ++j)                                                 \
      acc[(mqv) * 4 + ii][j] = __builtin_amdgcn_mfma_f32_16x16x32_f16(          \
          af[ii], bf[j], acc[(mqv) * 4 + ii][j], 0, 0, 0); } }
#define VM2 { asm volatile("s_waitcnt vmcnt(2)" ::: "memory");                  \
              __builtin_amdgcn_sched_barrier(0); }
#define VM0 { asm volatile("s_waitcnt vmcnt(0)" ::: "memory");                  \
              __builtin_amdgcn_sched_barrier(0); }
#define BAR  __builtin_amdgcn_s_barrier()
#define PRIO1 __builtin_amdgcn_s_setprio(1)
#define PRIO0 __builtin_amdgcn_s_setprio(0)

#pragma unroll
  for (int i = 0; i < 4; ++i) async16(sB + i * 4096, gB[i]);
#pragma unroll
  for (int i = 0; i < 4; ++i) async16(sA + i * 4096, gA[i]);
  VM0;
  BAR;

  for (int t = 0; t < NT; ++t) {
    const int buf = (t & 1) << 14;
    const int nbf = ((t + 1) & 1) << 14;
    const bool st = (t + 1 < NT);
    const int k0n = (t + 1) << 6;

    if (st) { async16(sB + nbf + 0 * 4096, gB[0] + k0n);
              async16(sB + nbf + 1 * 4096, gB[1] + k0n); }
    RDB(sw0); RDA(0, sw0);
    BAR;
    PRIO1; MM(0); PRIO0;
    if (t > 0) { if (st) VM2 else VM0 }
    BAR;
    if (st) { async16(sB + nbf + 2 * 4096, gB[2] + k0n);
              async16(sB + nbf + 3 * 4096, gB[3] + k0n); }
    RDA(1, sw0);
    BAR;
    PRIO1; MM(1); PRIO0;
    BAR;
    if (st) { async16(sA + nbf + 0 * 4096, gA[0] + k0n);
              async16(sA + nbf + 2 * 4096, gA[2] + k0n); }
    RDB(sw1); RDA(0, sw1);
    BAR;
    PRIO1; MM(0); PRIO0;
    BAR;
    if (st) { async16(sA + nbf + 1 * 4096, gA[1] + k0n);
              async16(sA + nbf + 3 * 4096, gA[3] + k0n); }
    RDA(1, sw1);
    BAR;
    PRIO1; MM(1); PRIO0;
    if (st) VM2;
    BAR;
  }
#undef RDA
#undef RDB
#undef MM
#undef VM2
#undef VM0
#undef BAR
#undef PRIO1
#undef PRIO0

  const int row0 = bm * 256 + wm * 128 + quad * 4;
  const int colT = bn * 256 + wn * 64 + m16;
#pragma unroll
  for (int ai = 0; ai < 8; ++ai)
#pragma unroll
    for (int j = 0; j < 4; ++j) {
      const int col = colT + j * 16;
      const float bcol = bias_heads[col];
#pragma unroll
      for (int r = 0; r < 4; ++r) {
        const int row = row0 + ai * 16 + r;
        float v = acc[ai][j][r] + bcol;
        if (col < 20)        out_upos[(size_t)row * 20 + col] = v;
        else if (col < 320)  out_xpos[(size_t)row * 300 + col - 20] = v;
        else if (col < 820)  out_attrs[(size_t)row * 500 + col - 320] = v;
      }
    }

  // ---- arcs: 64 rows per block, 512 threads = one full row per pass ----
  const int r0 = bm * 256 + bn * 64;
  const float bh = b_head[0];
  const float s2v = s2[((r0 >> 9) << 9) + tid];
  for (int rl = 0; rl < 64; ++rl) {
    const int row = r0 + rl;
    const float s1v = s1[row] + bh;
    float* orow = out_arcs + (size_t)row * 513;
    if (tid == 0) orow[0] = 0.f;
    orow[1 + tid] = s1v + s2v;
  }
}

// ---------------------------------------------------------------------------
extern "C" void kernel_launch(void* const* d_in, const int* in_sizes, int n_in,
                              void* d_out, int out_size, void* d_ws, size_t ws_size,
                              hipStream_t stream)
{
  const float* emb      = (const float*)d_in[0];   // [32,512,500]
  const float* hidden   = (const float*)d_in[1];   // [32,512,800]
  const int*   lang_ids = (const int*)d_in[2];     // [32]
  const float* lang_tab = (const float*)d_in[3];   // [8,100]
  const float* W_arc  = (const float*)d_in[4];
  const float* b_arc  = (const float*)d_in[5];
  const float* W_lab  = (const float*)d_in[6];
  const float* b_lab  = (const float*)d_in[7];
  const float* w_head = (const float*)d_in[8];
  const float* b_head = (const float*)d_in[9];
  const float* W_aux  = (const float*)d_in[10];
  const float* b_aux  = (const float*)d_in[11];
  const float* W_upos = (const float*)d_in[12];
  const float* b_upos = (const float*)d_in[13];
  const float* W_xpos = (const float*)d_in[14];
  const float* b_xpos = (const float*)d_in[15];
  const float* W_attrs = (const float*)d_in[16];
  const float* b_attrs = (const float*)d_in[17];

  char* ws = (char*)d_ws;
  f16* aux_cat = (f16*)(ws + 0);                  // 16384*640*2 = 20,971,520
  f16* W_proj  = (f16*)(ws + 20971520);           // 512*640*2   =    655,360
  f16* W_auxp  = (f16*)(ws + 21626880);           // 512*832*2   =    851,968
  f16* W_heads = (f16*)(ws + 22478848);           // 1024*640*2  =  1,310,720
  float* bias_proj  = (float*)(ws + 23789568);    // 512*4
  float* bias_aux   = (float*)(ws + 23791616);    // 512*4
  float* bias_heads = (float*)(ws + 23793664);    // 1024*4
  float* s1         = (float*)(ws + 23797760);    // 16384*4
  float* s2         = (float*)(ws + 23863296);    // 16384*4
  // total ws use: 23,928,832 bytes

  float* out       = (float*)d_out;
  float* out_arcs  = out;                 // 8,404,992
  float* out_label = out + 8404992;       // 6,553,600
  float* out_upos  = out + 14958592;      //   327,680
  float* out_xpos  = out + 15286272;      // 4,915,200
  float* out_attrs = out + 20201472;      // 8,192,000

  setup_kernel<<<1377, 256, 0, stream>>>(
      W_arc, b_arc, W_lab, b_lab, W_aux, b_aux,
      W_upos, b_upos, W_xpos, b_xpos, W_attrs, b_attrs,
      W_proj, W_auxp, W_heads, bias_proj, bias_aux, bias_heads);

  gemm01<<<dim3(64, 4), 512, 0, stream>>>(
      emb, hidden, lang_tab, lang_ids, W_proj, W_auxp, bias_proj, bias_aux,
      out_label, w_head, s1, s2, aux_cat);

  gemm2_arcs<<<dim3(64, 4), 512, 0, stream>>>(
      aux_cat, W_heads, bias_heads, s1, s2, b_head,
      out_arcs, out_upos, out_xpos, out_attrs);
}

// Round 5
// 274.324 us; speedup vs baseline: 1.2342x; 1.0331x over previous
//
#include <hip/hip_runtime.h>

// ===== Problem dims =====
// B=32, L=512 -> M = 16384 rows. Inputs fp32, OUTPUTS fp32.
// GEMM1(proj): A=[emb|lang] K=640 (reg-staged fp32->f16), N=512 pad, tanh,
//   fused s1/s2. GEMM1b(aux): A=hidden K=800 pad 832 (reg-staged), tanh,
//   writes aux_cat (+lang/pad cols from bny==2 epilogue).
// GEMM2(heads): A=aux_cat f16 (async16), N=820 pad 1024, arcs fused.
// 256x256 tile, BK=64, 8 waves. FREE-RUN schedule: ONE s_barrier per K-tile
// (all staging targets the opposite LDS buffer from all reads, so intra-tile
// phases need no inter-wave sync; waves co-schedule MFMA with ds_read/loads
// -- the m114 overlap). Explicit waits only at the tile boundary:
// vmcnt(0)+lgkmcnt(0) right BEFORE the barrier (publish async16/ds_write);
// A-reg dependency waits are compiler-inserted counted vmcnt.
// 3 launches: setup(weights+bias) -> gemm01 (64x4) -> gemm2+arcs (64x4).

using f16   = _Float16;
using f16x4 = __attribute__((ext_vector_type(4))) _Float16;
using f16x8 = __attribute__((ext_vector_type(8))) _Float16;  // 8 f16 (4 VGPRs)
using f32x4 = __attribute__((ext_vector_type(4))) float;     // MFMA acc

__device__ __forceinline__ f16 f2h(float f) { return (f16)f; }
__device__ __forceinline__ f16x4 cvt4(float4 v) {
  return f16x4{ f2h(v.x), f2h(v.y), f2h(v.z), f2h(v.w) };
}

// fast tanh: 1 - 2/(2^(2x*log2e)+1)
__device__ __forceinline__ float fast_tanh(float x) {
  float xc = fminf(fmaxf(x, -15.f), 15.f);
  float e  = __builtin_amdgcn_exp2f(xc * 2.885390081777927f);
  return 1.f - 2.f * __builtin_amdgcn_rcpf(e + 1.f);
}

// async global->LDS, 16B/lane; LDS dest = wave-uniform base + lane*16
__device__ __forceinline__ void async16(void* lds, const void* gp) {
  __builtin_amdgcn_global_load_lds(
      (const __attribute__((address_space(1))) unsigned int*)gp,
      (__attribute__((address_space(3))) unsigned int*)lds, 16, 0, 0);
}

// ---------------------------------------------------------------------------
// Setup (tiny): pack f16 weights + fp32 biases only.
//   W_proj[512,640] | W_auxp[512,832] | W_heads[1024,640]
// ---------------------------------------------------------------------------
__global__ __launch_bounds__(256) void setup_kernel(
    const float* __restrict__ W_arc, const float* __restrict__ b_arc,
    const float* __restrict__ W_lab, const float* __restrict__ b_lab,
    const float* __restrict__ W_aux, const float* __restrict__ b_aux,
    const float* __restrict__ W_upos, const float* __restrict__ b_upos,
    const float* __restrict__ W_xpos, const float* __restrict__ b_xpos,
    const float* __restrict__ W_attrs, const float* __restrict__ b_attrs,
    f16* __restrict__ W_proj, f16* __restrict__ W_auxp, f16* __restrict__ W_heads,
    float* __restrict__ bias_proj, float* __restrict__ bias_aux, float* __restrict__ bias_heads)
{
  const int blk = blockIdx.x, t = threadIdx.x;
  if (blk < 1376) {                          // 352,256 weight quads
    int w = blk * 256 + t;
    const float* src = nullptr;
    f16* dst;
    if (w < 81920) {                         // W_proj [512,640] : 160 q/row
      int n = w / 160, s = w - n * 160;
      dst = W_proj + (size_t)w * 4;
      if (s < 150 && n < 500)
        src = (n < 100 ? W_arc + (size_t)n * 600
                       : W_lab + (size_t)(n - 100) * 600) + s * 4;
    } else if (w < 81920 + 106496) {         // W_auxp [512,832] : 208 q/row
      int w2 = w - 81920;
      int n = w2 / 208, s = w2 - n * 208;
      dst = W_auxp + (size_t)w2 * 4;
      if (s < 200 && n < 500) src = W_aux + (size_t)n * 800 + s * 4;
    } else {                                 // W_heads [1024,640] : 160 q/row
      int w3 = w - (81920 + 106496);
      int n = w3 / 160, s = w3 - n * 160;
      dst = W_heads + (size_t)w3 * 4;
      if (s < 150 && n < 820)
        src = (n < 20 ? W_upos + (size_t)n * 600
              : n < 320 ? W_xpos + (size_t)(n - 20) * 600
                        : W_attrs + (size_t)(n - 320) * 600) + s * 4;
    }
    f16x4 h = { (f16)0.f, (f16)0.f, (f16)0.f, (f16)0.f };
    if (src) h = cvt4(*(const float4*)src);
    *(f16x4*)dst = h;
    return;
  }
  for (int idx = t; idx < 2048; idx += 256) {      // ---- biases ----
    if (idx < 512) {
      float v = 0.f;
      if (idx < 100)      v = b_arc[idx];
      else if (idx < 500) v = b_lab[idx - 100];
      bias_proj[idx] = v;
    } else if (idx < 1024) {
      int i = idx - 512;
      bias_aux[i] = (i < 500) ? b_aux[i] : 0.f;
    } else {
      int i = idx - 1024; float v = 0.f;
      if (i < 20)       v = b_upos[i];
      else if (i < 320) v = b_xpos[i - 20];
      else if (i < 820) v = b_attrs[i - 320];
      bias_heads[i] = v;
    }
  }
}

// ---------------------------------------------------------------------------
// Fused GEMM0+GEMM1, grid (64, 4), 512 threads. A reg-staged from fp32.
//   bny<2 : proj A=[emb|lang|pad] K=640 NT=10; cols[100,500)->out_label;
//           bny==0: fused s1/s2 head dots
//   bny>=2: aux  A=hidden pad     K=832 NT=13; cols[0,500)->aux_cat;
//           bny==2 also writes aux_cat lang/pad cols [500,640)
// ---------------------------------------------------------------------------
__global__ __launch_bounds__(512, 2) void gemm01(
    const float* __restrict__ emb, const float* __restrict__ hidden,
    const float* __restrict__ lang_table, const int* __restrict__ lang_ids,
    const f16* __restrict__ W_proj, const f16* __restrict__ W_auxp,
    const float* __restrict__ bias_proj, const float* __restrict__ bias_aux,
    float* __restrict__ out_label, const float* __restrict__ w_head,
    float* __restrict__ s1, float* __restrict__ s2, f16* __restrict__ aux_cat)
{
  __shared__ __align__(16) f16 ldsA[2 * 16384];
  __shared__ __align__(16) f16 ldsB[2 * 16384];
  __shared__ float s1red[2][256], s2red[2][256];

  const int tid  = threadIdx.x;
  const int lane = tid & 63;
  const int wave = tid >> 6;                 // 0..7
  const int wm = wave >> 2, wn = wave & 3;   // 2M x 4N
  const int m16 = lane & 15, quad = lane >> 4;
  const int bm  = blockIdx.x;
  const int bny = blockIdx.y;                // 0..3
  const bool is0 = (bny < 2);
  const int bn  = is0 ? bny : bny - 2;
  const int K   = is0 ? 640 : 832;
  const int NT  = is0 ? 10 : 13;

  // ---- B staging (async16, pre-swizzled source) ----
  const int sr = lane >> 3;
  const int ssB = (lane & 7) ^ sr;
  const f16* Bmat = is0 ? W_proj : W_auxp;
  const f16* gB[4];
#pragma unroll
  for (int i = 0; i < 4; ++i)
    gB[i] = Bmat + (size_t)(bn * 256 + i * 64 + wave * 8 + sr) * K + ssB * 8;
  f16* sB = ldsB + wave * 512;

  // ---- A reg-staging: lane owns 4 chunks (rows wave*32+i*8+(lane>>3),
  //      slot ssA=lane&7); lang row is block-uniform (batch = bm>>1). ----
  const int ssA = lane & 7;
  const float* lrow = lang_table + (size_t)lang_ids[bm >> 1] * 100;
  const float* srcA[4];
  int dstA[4];
#pragma unroll
  for (int i = 0; i < 4; ++i) {
    const int rowA = wave * 32 + i * 8 + (lane >> 3);
    const int grow = bm * 256 + rowA;
    srcA[i] = is0 ? emb + (size_t)grow * 500 : hidden + (size_t)grow * 800;
    dstA[i] = rowA * 64 + ((ssA ^ (rowA & 7)) * 8);
  }
  float4 va[4], vb[4];

  // ---- ds_read bases ----
  const int aBase = (wm * 128 + m16) * 64;
  const int bBase = (wn * 64  + m16) * 64;
  const int sw0 = ((quad)     ^ (m16 & 7)) * 8;
  const int sw1 = ((4 | quad) ^ (m16 & 7)) * 8;

  f32x4 acc[8][4] = {};
  f16x8 af[4], bf[4];

#define ASTAGE(tt) do { const int k0b = (tt) * 64 + ssA * 8;                    \
    _Pragma("unroll")                                                           \
    for (int i2 = 0; i2 < 4; ++i2) {                                            \
      float4 x0 = {0.f,0.f,0.f,0.f}, x1 = {0.f,0.f,0.f,0.f};                    \
      if (is0) {                                                                \
        if (k0b < 500) { x0 = *(const float4*)(srcA[i2] + k0b);                 \
          x1 = (k0b + 4 < 500) ? *(const float4*)(srcA[i2] + k0b + 4)           \
                               : *(const float4*)(lrow); }                      \
        else if (k0b < 600) { x0 = *(const float4*)(lrow + k0b - 500);          \
                              x1 = *(const float4*)(lrow + k0b - 496); }        \
      } else if (k0b < 800) { x0 = *(const float4*)(srcA[i2] + k0b);            \
                              x1 = *(const float4*)(srcA[i2] + k0b + 4); }      \
      va[i2] = x0; vb[i2] = x1; } } while (0)

#define AWRITE(nbf) do { _Pragma("unroll")                                      \
    for (int i2 = 0; i2 < 4; ++i2) {                                            \
      f16x8 hw = { f2h(va[i2].x), f2h(va[i2].y), f2h(va[i2].z), f2h(va[i2].w),  \
                   f2h(vb[i2].x), f2h(vb[i2].y), f2h(vb[i2].z), f2h(vb[i2].w) };\
      *(f16x8*)&ldsA[(nbf) + dstA[i2]] = hw; } } while (0)

#define BWISSUE(k0n, nbf) do {                                                  \
    async16(sB + (nbf) + 0 * 4096, gB[0] + (k0n));                              \
    async16(sB + (nbf) + 1 * 4096, gB[1] + (k0n));                              \
    async16(sB + (nbf) + 2 * 4096, gB[2] + (k0n));                              \
    async16(sB + (nbf) + 3 * 4096, gB[3] + (k0n)); } while (0)

#define RDA(mqv, sw) { _Pragma("unroll")                                        \
  for (int ii = 0; ii < 4; ++ii)                                                \
    af[ii] = *(const f16x8*)&ldsA[buf + aBase + (mqv) * 4096 + ii * 1024 + (sw)]; }
#define RDB(sw) { _Pragma("unroll")                                             \
  for (int j = 0; j < 4; ++j)                                                   \
    bf[j] = *(const f16x8*)&ldsB[buf + bBase + j * 1024 + (sw)]; }
#define MM(mqv) { _Pragma("unroll")                                             \
  for (int ii = 0; ii < 4; ++ii) { _Pragma("unroll")                            \
    for (int j = 0; j < 4; ++j)                                                 \
      acc[(mqv) * 4 + ii][j] = __builtin_amdgcn_mfma_f32_16x16x32_f16(          \
          af[ii], bf[j], acc[(mqv) * 4 + ii][j], 0, 0, 0); } }
#define VM0  asm volatile("s_waitcnt vmcnt(0)" ::: "memory")
#define LGK0 asm volatile("s_waitcnt lgkmcnt(0)" ::: "memory")
#define BAR  __builtin_amdgcn_s_barrier()
#define PRIO1 __builtin_amdgcn_s_setprio(1)
#define PRIO0 __builtin_amdgcn_s_setprio(0)

  // ---- prologue: tile 0 (A loads first so auto-wait before AWRITE is
  //      counted, leaving the 4 async16 in flight until the explicit VM0) ----
  ASTAGE(0);
  BWISSUE(0, 0);
  AWRITE(0);                 // compiler inserts counted vmcnt for va/vb
  VM0;                       // retire async16 (publish ldsB[0])
  LGK0;                      // publish ds_writes
  BAR;

  for (int t = 0; t < NT; ++t) {
    const int buf = (t & 1) << 14;           // *16384
    const int nbf = ((t + 1) & 1) << 14;
    const bool st = (t + 1 < NT);
    const int k0n = (t + 1) << 6;

    // ---- free-run tile body: no intra-tile barriers ----
    // P0: reads of tile t + issue ALL staging for t+1 (A regs, B async16)
    RDB(sw0); RDA(0, sw0);
    if (st) { ASTAGE(t + 1); BWISSUE(k0n, nbf); }
    PRIO1; MM(0); PRIO0;
    // P1
    RDA(1, sw0);
    PRIO1; MM(1); PRIO0;
    // P2
    RDB(sw1); RDA(0, sw1);
    PRIO1; MM(0); PRIO0;
    // P3 + land A into LDS (auto counted vmcnt before first cvt/ds_write)
    RDA(1, sw1);
    PRIO1; MM(1); PRIO0;
    if (st) AWRITE(nbf);
    VM0;                      // retire async16(t+1) -> publish ldsB[nbf]
    LGK0;                     // publish AWRITE ds_writes
    BAR;                      // single per-tile barrier
  }
#undef ASTAGE
#undef AWRITE
#undef BWISSUE
#undef RDA
#undef RDB
#undef MM
#undef VM0
#undef LGK0
#undef BAR
#undef PRIO1
#undef PRIO0

  // ---- epilogue ----
  const int row0 = bm * 256 + wm * 128 + quad * 4;
  const int colT = bn * 256 + wn * 64 + m16;

  if (is0) {
    const float* bias = bias_proj;
    float p1[8][4] = {}, p2[8][4] = {};
    const bool haveHead = (bn == 0);
#pragma unroll
    for (int ai = 0; ai < 8; ++ai) {
#pragma unroll
      for (int j = 0; j < 4; ++j) {
        const int col = colT + j * 16;
        const float bcol = bias[col];
        float w1c = 0.f, w2c = 0.f;
        if (haveHead && col < 100) { w1c = w_head[col]; w2c = w_head[100 + col]; }
#pragma unroll
        for (int r = 0; r < 4; ++r) {
          const int row = row0 + ai * 16 + r;
          float v = fast_tanh(acc[ai][j][r] + bcol);
          if (col >= 100 && col < 500) out_label[(size_t)row * 400 + col - 100] = v;
          p1[ai][r] += v * w1c;
          p2[ai][r] += v * w2c;
        }
      }
    }
    if (haveHead) {
      if (wn < 2) {
#pragma unroll
        for (int d = 1; d < 16; d <<= 1)
#pragma unroll
          for (int ai = 0; ai < 8; ++ai)
#pragma unroll
            for (int r = 0; r < 4; ++r) {
              p1[ai][r] += __shfl_xor(p1[ai][r], d);
              p2[ai][r] += __shfl_xor(p2[ai][r], d);
            }
        if (m16 == 0) {
#pragma unroll
          for (int ai = 0; ai < 8; ++ai)
#pragma unroll
            for (int r = 0; r < 4; ++r) {
              int rl = wm * 128 + ai * 16 + quad * 4 + r;
              s1red[wn][rl] = p1[ai][r];
              s2red[wn][rl] = p2[ai][r];
            }
        }
      }
      __syncthreads();
      if (tid < 256) s1[bm * 256 + tid] = s1red[0][tid] + s1red[1][tid];
      else { int t2 = tid - 256; s2[bm * 256 + t2] = s2red[0][t2] + s2red[1][t2]; }
    }
  } else {
    const float* bias = bias_aux;
#pragma unroll
    for (int ai = 0; ai < 8; ++ai)
#pragma unroll
      for (int j = 0; j < 4; ++j) {
        const int col = colT + j * 16;
        if (col < 500) {
          const float bcol = bias[col];
#pragma unroll
          for (int r = 0; r < 4; ++r) {
            const int row = row0 + ai * 16 + r;
            aux_cat[(size_t)row * 640 + col] = f2h(fast_tanh(acc[ai][j][r] + bcol));
          }
        }
      }
    if (bn == 0) {                           // bny==2: lang/pad cols [500,640)
      for (int idx = tid; idx < 256 * 35; idx += 512) {
        int rr = idx / 35, qq = idx - rr * 35;
        int col = 500 + 4 * qq;
        f16x4 h = { (f16)0.f, (f16)0.f, (f16)0.f, (f16)0.f };
        if (col < 600) h = cvt4(*(const float4*)(lrow + col - 500));
        *(f16x4*)(aux_cat + (size_t)(bm * 256 + rr) * 640 + col) = h;
      }
    }
  }
}

// ---------------------------------------------------------------------------
// Fused GEMM2 + arcs, grid (64, 4), 512 threads, free-run 1-barrier/tile:
//   heads GEMM A=aux_cat[16384,640] B=W_heads[1024,640] K=640 NT=10;
//   cols<20 upos | <320 xpos | <820 attrs. Then arcs rows [bm*256+bn*64,+64).
// ---------------------------------------------------------------------------
__global__ __launch_bounds__(512, 2) void gemm2_arcs(
    const f16* __restrict__ aux_cat, const f16* __restrict__ W_heads,
    const float* __restrict__ bias_heads,
    const float* __restrict__ s1, const float* __restrict__ s2,
    const float* __restrict__ b_head,
    float* __restrict__ out_arcs, float* __restrict__ out_upos,
    float* __restrict__ out_xpos, float* __restrict__ out_attrs)
{
  __shared__ __align__(16) f16 ldsA[2 * 16384];
  __shared__ __align__(16) f16 ldsB[2 * 16384];

  const int tid  = threadIdx.x;
  const int lane = tid & 63;
  const int wave = tid >> 6;
  const int wm = wave >> 2, wn = wave & 3;
  const int m16 = lane & 15, quad = lane >> 4;
  const int bm = blockIdx.x, bn = blockIdx.y;
  const int K = 640, NT = 10;

  const int sr = lane >> 3;
  const int ss = (lane & 7) ^ sr;
  const f16* gA[4]; const f16* gB[4];
#pragma unroll
  for (int i = 0; i < 4; ++i) {
    gA[i] = aux_cat + (size_t)(bm * 256 + i * 64 + wave * 8 + sr) * K + ss * 8;
    gB[i] = W_heads + (size_t)(bn * 256 + i * 64 + wave * 8 + sr) * K + ss * 8;
  }
  f16* sA = ldsA + wave * 512;
  f16* sB = ldsB + wave * 512;

  const int aBase = (wm * 128 + m16) * 64;
  const int bBase = (wn * 64  + m16) * 64;
  const int sw0 = ((quad)     ^ (m16 & 7)) * 8;
  const int sw1 = ((4 | quad) ^ (m16 & 7)) * 8;

  f32x4 acc[8][4] = {};
  f16x8 af[4], bf[4];

#define STAGE8(k0n, nbf) do {                                                   \
    async16(sA + (nbf) + 0 * 4096, gA[0] + (k0n));                              \
    async16(sA + (nbf) + 1 * 4096, gA[1] + (k0n));                              \
    async16(sA + (nbf) + 2 * 4096, gA[2] + (k0n));                              \
    async16(sA + (nbf) + 3 * 4096, gA[3] + (k0n));                              \
    async16(sB + (nbf) + 0 * 4096, gB[0] + (k0n));                              \
    async16(sB + (nbf) + 1 * 4096, gB[1] + (k0n));                              \
    async16(sB + (nbf) + 2 * 4096, gB[2] + (k0n));                              \
    async16(sB + (nbf) + 3 * 4096, gB[3] + (k0n)); } while (0)

#define RDA(mqv, sw) { _Pragma("unroll")                                        \
  for (int ii = 0; ii < 4; ++ii)                                                \
    af[ii] = *(const f16x8*)&ldsA[buf + aBase + (mqv) * 4096 + ii * 1024 + (sw)]; }
#define RDB(sw) { _Pragma("unroll")                                             \
  for (int j = 0; j < 4; ++j)                                                   \
    bf[j] = *(const f16x8*)&ldsB[buf + bBase + j * 1024 + (sw)]; }
#define MM(mqv) { _Pragma("unroll")                                             \
  for (int ii = 0; ii < 4; ++ii) { _Pragma("unroll")                            \
    for (int j = 0; j < 4; ++j)                                                 \
      acc[(mqv) * 4 + ii][j] = __builtin_amdgcn_mfma_f32_16x16x32_f16(          \
          af[ii], bf[j], acc[(mqv) * 4 + ii][j], 0, 0, 0); } }
#define VM0  asm volatile("s_waitcnt vmcnt(0)" ::: "memory")
#define BAR  __builtin_amdgcn_s_barrier()
#define PRIO1 __builtin_amdgcn_s_setprio(1)
#define PRIO0 __builtin_amdgcn_s_setprio(0)

  STAGE8(0, 0);
  VM0;
  BAR;

  for (int t = 0; t < NT; ++t) {
    const int buf = (t & 1) << 14;
    const int nbf = ((t + 1) & 1) << 14;
    const bool st = (t + 1 < NT);
    const int k0n = (t + 1) << 6;

    RDB(sw0); RDA(0, sw0);
    if (st) STAGE8(k0n, nbf);
    PRIO1; MM(0); PRIO0;
    RDA(1, sw0);
    PRIO1; MM(1); PRIO0;
    RDB(sw1); RDA(0, sw1);
    PRIO1; MM(0); PRIO0;
    RDA(1, sw1);
    PRIO1; MM(1); PRIO0;
    VM0;                      // retire async16(t+1) -> publish lds[nbf]
    BAR;                      // single per-tile barrier
  }
#undef STAGE8
#undef RDA
#undef RDB
#undef MM
#undef VM0
#undef BAR
#undef PRIO1
#undef PRIO0

  const int row0 = bm * 256 + wm * 128 + quad * 4;
  const int colT = bn * 256 + wn * 64 + m16;
#pragma unroll
  for (int ai = 0; ai < 8; ++ai)
#pragma unroll
    for (int j = 0; j < 4; ++j) {
      const int col = colT + j * 16;
      const float bcol = bias_heads[col];
#pragma unroll
      for (int r = 0; r < 4; ++r) {
        const int row = row0 + ai * 16 + r;
        float v = acc[ai][j][r] + bcol;
        if (col < 20)        out_upos[(size_t)row * 20 + col] = v;
        else if (col < 320)  out_xpos[(size_t)row * 300 + col - 20] = v;
        else if (col < 820)  out_attrs[(size_t)row * 500 + col - 320] = v;
      }
    }

  // ---- arcs: 64 rows per block, 512 threads = one full row per pass ----
  const int r0 = bm * 256 + bn * 64;
  const float bh = b_head[0];
  const float s2v = s2[((r0 >> 9) << 9) + tid];
  for (int rl = 0; rl < 64; ++rl) {
    const int row = r0 + rl;
    const float s1v = s1[row] + bh;
    float* orow = out_arcs + (size_t)row * 513;
    if (tid == 0) orow[0] = 0.f;
    orow[1 + tid] = s1v + s2v;
  }
}

// ---------------------------------------------------------------------------
extern "C" void kernel_launch(void* const* d_in, const int* in_sizes, int n_in,
                              void* d_out, int out_size, void* d_ws, size_t ws_size,
                              hipStream_t stream)
{
  const float* emb      = (const float*)d_in[0];   // [32,512,500]
  const float* hidden   = (const float*)d_in[1];   // [32,512,800]
  const int*   lang_ids = (const int*)d_in[2];     // [32]
  const float* lang_tab = (const float*)d_in[3];   // [8,100]
  const float* W_arc  = (const float*)d_in[4];
  const float* b_arc  = (const float*)d_in[5];
  const float* W_lab  = (const float*)d_in[6];
  const float* b_lab  = (const float*)d_in[7];
  const float* w_head = (const float*)d_in[8];
  const float* b_head = (const float*)d_in[9];
  const float* W_aux  = (const float*)d_in[10];
  const float* b_aux  = (const float*)d_in[11];
  const float* W_upos = (const float*)d_in[12];
  const float* b_upos = (const float*)d_in[13];
  const float* W_xpos = (const float*)d_in[14];
  const float* b_xpos = (const float*)d_in[15];
  const float* W_attrs = (const float*)d_in[16];
  const float* b_attrs = (const float*)d_in[17];

  char* ws = (char*)d_ws;
  f16* aux_cat = (f16*)(ws + 0);                  // 16384*640*2 = 20,971,520
  f16* W_proj  = (f16*)(ws + 20971520);           // 512*640*2   =    655,360
  f16* W_auxp  = (f16*)(ws + 21626880);           // 512*832*2   =    851,968
  f16* W_heads = (f16*)(ws + 22478848);           // 1024*640*2  =  1,310,720
  float* bias_proj  = (float*)(ws + 23789568);    // 512*4
  float* bias_aux   = (float*)(ws + 23791616);    // 512*4
  float* bias_heads = (float*)(ws + 23793664);    // 1024*4
  float* s1         = (float*)(ws + 23797760);    // 16384*4
  float* s2         = (float*)(ws + 23863296);    // 16384*4
  // total ws use: 23,928,832 bytes

  float* out       = (float*)d_out;
  float* out_arcs  = out;                 // 8,404,992
  float* out_label = out + 8404992;       // 6,553,600
  float* out_upos  = out + 14958592;      //   327,680
  float* out_xpos  = out + 15286272;      // 4,915,200
  float* out_attrs = out + 20201472;      // 8,192,000

  setup_kernel<<<1377, 256, 0, stream>>>(
      W_arc, b_arc, W_lab, b_lab, W_aux, b_aux,
      W_upos, b_upos, W_xpos, b_xpos, W_attrs, b_attrs,
      W_proj, W_auxp, W_heads, bias_proj, bias_aux, bias_heads);

  gemm01<<<dim3(64, 4), 512, 0, stream>>>(
      emb, hidden, lang_tab, lang_ids, W_proj, W_auxp, bias_proj, bias_aux,
      out_label, w_head, s1, s2, aux_cat);

  gemm2_arcs<<<dim3(64, 4), 512, 0, stream>>>(
      aux_cat, W_heads, bias_heads, s1, s2, b_head,
      out_arcs, out_upos, out_xpos, out_attrs);
}

// Round 6
// 266.763 us; speedup vs baseline: 1.2692x; 1.0283x over previous
//
#include <hip/hip_runtime.h>

// ===== Problem dims =====
// B=32, L=512 -> M = 16384 rows. Inputs fp32, OUTPUTS fp32.
// GEMM1(proj): A=[emb|lang] K=640 (reg-staged fp32->f16), N=512 pad, tanh,
//   fused s1/s2. GEMM1b(aux): A=hidden K=800 pad 832 (reg-staged), tanh,
//   writes aux_cat (+lang/pad cols from bny==2 epilogue).
// GEMM2(heads): A=aux_cat f16 (async16), N=820 pad 1024, arcs fused.
// 256x256 tile, BK=64, 8 waves. FREE-RUN schedule: ONE s_barrier per K-tile.
// gemm01 A-landing pinned by hand (R5 post-mortem): sched_barrier after
// ASTAGE (A-loads issue before B async16), then at end-of-tile
// sched_barrier + s_waitcnt vmcnt(4) + sched_barrier + AWRITE -- vmcnt
// retires in issue order, so <=4 outstanding => all A-loads landed while
// the 4 async16 stay in flight until the explicit VM0 before the barrier.
// 3 launches: setup(weights+bias) -> gemm01 (64x4) -> gemm2+arcs (64x4).

using f16   = _Float16;
using f16x4 = __attribute__((ext_vector_type(4))) _Float16;
using f16x8 = __attribute__((ext_vector_type(8))) _Float16;  // 8 f16 (4 VGPRs)
using f32x4 = __attribute__((ext_vector_type(4))) float;     // MFMA acc

__device__ __forceinline__ f16 f2h(float f) { return (f16)f; }
__device__ __forceinline__ f16x4 cvt4(float4 v) {
  return f16x4{ f2h(v.x), f2h(v.y), f2h(v.z), f2h(v.w) };
}

// fast tanh: 1 - 2/(2^(2x*log2e)+1)
__device__ __forceinline__ float fast_tanh(float x) {
  float xc = fminf(fmaxf(x, -15.f), 15.f);
  float e  = __builtin_amdgcn_exp2f(xc * 2.885390081777927f);
  return 1.f - 2.f * __builtin_amdgcn_rcpf(e + 1.f);
}

// async global->LDS, 16B/lane; LDS dest = wave-uniform base + lane*16
__device__ __forceinline__ void async16(void* lds, const void* gp) {
  __builtin_amdgcn_global_load_lds(
      (const __attribute__((address_space(1))) unsigned int*)gp,
      (__attribute__((address_space(3))) unsigned int*)lds, 16, 0, 0);
}

// ---------------------------------------------------------------------------
// Setup (tiny): pack f16 weights + fp32 biases only.
//   W_proj[512,640] | W_auxp[512,832] | W_heads[1024,640]
// ---------------------------------------------------------------------------
__global__ __launch_bounds__(256) void setup_kernel(
    const float* __restrict__ W_arc, const float* __restrict__ b_arc,
    const float* __restrict__ W_lab, const float* __restrict__ b_lab,
    const float* __restrict__ W_aux, const float* __restrict__ b_aux,
    const float* __restrict__ W_upos, const float* __restrict__ b_upos,
    const float* __restrict__ W_xpos, const float* __restrict__ b_xpos,
    const float* __restrict__ W_attrs, const float* __restrict__ b_attrs,
    f16* __restrict__ W_proj, f16* __restrict__ W_auxp, f16* __restrict__ W_heads,
    float* __restrict__ bias_proj, float* __restrict__ bias_aux, float* __restrict__ bias_heads)
{
  const int blk = blockIdx.x, t = threadIdx.x;
  if (blk < 1376) {                          // 352,256 weight quads
    int w = blk * 256 + t;
    const float* src = nullptr;
    f16* dst;
    if (w < 81920) {                         // W_proj [512,640] : 160 q/row
      int n = w / 160, s = w - n * 160;
      dst = W_proj + (size_t)w * 4;
      if (s < 150 && n < 500)
        src = (n < 100 ? W_arc + (size_t)n * 600
                       : W_lab + (size_t)(n - 100) * 600) + s * 4;
    } else if (w < 81920 + 106496) {         // W_auxp [512,832] : 208 q/row
      int w2 = w - 81920;
      int n = w2 / 208, s = w2 - n * 208;
      dst = W_auxp + (size_t)w2 * 4;
      if (s < 200 && n < 500) src = W_aux + (size_t)n * 800 + s * 4;
    } else {                                 // W_heads [1024,640] : 160 q/row
      int w3 = w - (81920 + 106496);
      int n = w3 / 160, s = w3 - n * 160;
      dst = W_heads + (size_t)w3 * 4;
      if (s < 150 && n < 820)
        src = (n < 20 ? W_upos + (size_t)n * 600
              : n < 320 ? W_xpos + (size_t)(n - 20) * 600
                        : W_attrs + (size_t)(n - 320) * 600) + s * 4;
    }
    f16x4 h = { (f16)0.f, (f16)0.f, (f16)0.f, (f16)0.f };
    if (src) h = cvt4(*(const float4*)src);
    *(f16x4*)dst = h;
    return;
  }
  for (int idx = t; idx < 2048; idx += 256) {      // ---- biases ----
    if (idx < 512) {
      float v = 0.f;
      if (idx < 100)      v = b_arc[idx];
      else if (idx < 500) v = b_lab[idx - 100];
      bias_proj[idx] = v;
    } else if (idx < 1024) {
      int i = idx - 512;
      bias_aux[i] = (i < 500) ? b_aux[i] : 0.f;
    } else {
      int i = idx - 1024; float v = 0.f;
      if (i < 20)       v = b_upos[i];
      else if (i < 320) v = b_xpos[i - 20];
      else if (i < 820) v = b_attrs[i - 320];
      bias_heads[i] = v;
    }
  }
}

// ---------------------------------------------------------------------------
// Fused GEMM0+GEMM1, grid (64, 4), 512 threads. A reg-staged from fp32.
//   bny<2 : proj A=[emb|lang|pad] K=640 NT=10; cols[100,500)->out_label;
//           bny==0: fused s1/s2 head dots
//   bny>=2: aux  A=hidden pad     K=832 NT=13; cols[0,500)->aux_cat;
//           bny==2 also writes aux_cat lang/pad cols [500,640)
// ---------------------------------------------------------------------------
__global__ __launch_bounds__(512, 2) void gemm01(
    const float* __restrict__ emb, const float* __restrict__ hidden,
    const float* __restrict__ lang_table, const int* __restrict__ lang_ids,
    const f16* __restrict__ W_proj, const f16* __restrict__ W_auxp,
    const float* __restrict__ bias_proj, const float* __restrict__ bias_aux,
    float* __restrict__ out_label, const float* __restrict__ w_head,
    float* __restrict__ s1, float* __restrict__ s2, f16* __restrict__ aux_cat)
{
  __shared__ __align__(16) f16 ldsA[2 * 16384];
  __shared__ __align__(16) f16 ldsB[2 * 16384];
  __shared__ float s1red[2][256], s2red[2][256];

  const int tid  = threadIdx.x;
  const int lane = tid & 63;
  const int wave = tid >> 6;                 // 0..7
  const int wm = wave >> 2, wn = wave & 3;   // 2M x 4N
  const int m16 = lane & 15, quad = lane >> 4;
  const int bm  = blockIdx.x;
  const int bny = blockIdx.y;                // 0..3
  const bool is0 = (bny < 2);
  const int bn  = is0 ? bny : bny - 2;
  const int K   = is0 ? 640 : 832;
  const int NT  = is0 ? 10 : 13;

  // ---- B staging (async16, pre-swizzled source) ----
  const int sr = lane >> 3;
  const int ssB = (lane & 7) ^ sr;
  const f16* Bmat = is0 ? W_proj : W_auxp;
  const f16* gB[4];
#pragma unroll
  for (int i = 0; i < 4; ++i)
    gB[i] = Bmat + (size_t)(bn * 256 + i * 64 + wave * 8 + sr) * K + ssB * 8;
  f16* sB = ldsB + wave * 512;

  // ---- A reg-staging: lane owns 4 chunks (rows wave*32+i*8+(lane>>3),
  //      slot ssA=lane&7); lang row is block-uniform (batch = bm>>1). ----
  const int ssA = lane & 7;
  const float* lrow = lang_table + (size_t)lang_ids[bm >> 1] * 100;
  const float* srcA[4];
  int dstA[4];
#pragma unroll
  for (int i = 0; i < 4; ++i) {
    const int rowA = wave * 32 + i * 8 + (lane >> 3);
    const int grow = bm * 256 + rowA;
    srcA[i] = is0 ? emb + (size_t)grow * 500 : hidden + (size_t)grow * 800;
    dstA[i] = rowA * 64 + ((ssA ^ (rowA & 7)) * 8);
  }
  float4 va[4], vb[4];

  // ---- ds_read bases ----
  const int aBase = (wm * 128 + m16) * 64;
  const int bBase = (wn * 64  + m16) * 64;
  const int sw0 = ((quad)     ^ (m16 & 7)) * 8;
  const int sw1 = ((4 | quad) ^ (m16 & 7)) * 8;

  f32x4 acc[8][4] = {};
  f16x8 af[4], bf[4];

#define ASTAGE(tt) do { const int k0b = (tt) * 64 + ssA * 8;                    \
    _Pragma("unroll")                                                           \
    for (int i2 = 0; i2 < 4; ++i2) {                                            \
      float4 x0 = {0.f,0.f,0.f,0.f}, x1 = {0.f,0.f,0.f,0.f};                    \
      if (is0) {                                                                \
        if (k0b < 500) { x0 = *(const float4*)(srcA[i2] + k0b);                 \
          x1 = (k0b + 4 < 500) ? *(const float4*)(srcA[i2] + k0b + 4)           \
                               : *(const float4*)(lrow); }                      \
        else if (k0b < 600) { x0 = *(const float4*)(lrow + k0b - 500);          \
                              x1 = *(const float4*)(lrow + k0b - 496); }        \
      } else if (k0b < 800) { x0 = *(const float4*)(srcA[i2] + k0b);            \
                              x1 = *(const float4*)(srcA[i2] + k0b + 4); }      \
      va[i2] = x0; vb[i2] = x1; } } while (0)

#define AWRITE(nbf) do { _Pragma("unroll")                                      \
    for (int i2 = 0; i2 < 4; ++i2) {                                            \
      f16x8 hw = { f2h(va[i2].x), f2h(va[i2].y), f2h(va[i2].z), f2h(va[i2].w),  \
                   f2h(vb[i2].x), f2h(vb[i2].y), f2h(vb[i2].z), f2h(vb[i2].w) };\
      *(f16x8*)&ldsA[(nbf) + dstA[i2]] = hw; } } while (0)

#define BWISSUE(k0n, nbf) do {                                                  \
    async16(sB + (nbf) + 0 * 4096, gB[0] + (k0n));                              \
    async16(sB + (nbf) + 1 * 4096, gB[1] + (k0n));                              \
    async16(sB + (nbf) + 2 * 4096, gB[2] + (k0n));                              \
    async16(sB + (nbf) + 3 * 4096, gB[3] + (k0n)); } while (0)

#define RDA(mqv, sw) { _Pragma("unroll")                                        \
  for (int ii = 0; ii < 4; ++ii)                                                \
    af[ii] = *(const f16x8*)&ldsA[buf + aBase + (mqv) * 4096 + ii * 1024 + (sw)]; }
#define RDB(sw) { _Pragma("unroll")                                             \
  for (int j = 0; j < 4; ++j)                                                   \
    bf[j] = *(const f16x8*)&ldsB[buf + bBase + j * 1024 + (sw)]; }
#define MM(mqv) { _Pragma("unroll")                                             \
  for (int ii = 0; ii < 4; ++ii) { _Pragma("unroll")                            \
    for (int j = 0; j < 4; ++j)                                                 \
      acc[(mqv) * 4 + ii][j] = __builtin_amdgcn_mfma_f32_16x16x32_f16(          \
          af[ii], bf[j], acc[(mqv) * 4 + ii][j], 0, 0, 0); } }
#define SBAR __builtin_amdgcn_sched_barrier(0)
#define VM4  asm volatile("s_waitcnt vmcnt(4)" ::: "memory")
#define VM0  asm volatile("s_waitcnt vmcnt(0)" ::: "memory")
#define LGK0 asm volatile("s_waitcnt lgkmcnt(0)" ::: "memory")
#define BAR  __builtin_amdgcn_s_barrier()
#define PRIO1 __builtin_amdgcn_s_setprio(1)
#define PRIO0 __builtin_amdgcn_s_setprio(0)

  // ---- prologue: tile 0. A-loads first (issue-order pinned), then B
  //      async16; vmcnt(4) => all A landed, async16 still flying. ----
  ASTAGE(0);
  SBAR;
  BWISSUE(0, 0);
  SBAR; VM4; SBAR;
  AWRITE(0);
  VM0;                       // retire async16 (publish ldsB[0])
  LGK0;                      // publish ds_writes
  BAR;

  for (int t = 0; t < NT; ++t) {
    const int buf = (t & 1) << 14;           // *16384
    const int nbf = ((t + 1) & 1) << 14;
    const bool st = (t + 1 < NT);
    const int k0n = (t + 1) << 6;

    // ---- free-run tile body: no intra-tile barriers ----
    // P0: reads of tile t + issue ALL staging for t+1 (A regs first, pinned)
    RDB(sw0); RDA(0, sw0);
    if (st) ASTAGE(t + 1);
    SBAR;                      // A-loads issue before B async16
    if (st) BWISSUE(k0n, nbf);
    PRIO1; MM(0); PRIO0;
    // P1
    RDA(1, sw0);
    PRIO1; MM(1); PRIO0;
    // P2
    RDB(sw1); RDA(0, sw1);
    PRIO1; MM(0); PRIO0;
    // P3
    RDA(1, sw1);
    PRIO1; MM(1); PRIO0;
    // land A into LDS: pinned AFTER the MFMA clusters (R5 post-mortem:
    // unpinned, the compiler sinks this wait to right after ASTAGE and
    // serializes full HBM latency into every tile)
    if (st) {
      SBAR; VM4; SBAR;         // all 8 A-loads retired; 4 async16 in flight
      AWRITE(nbf);
    }
    VM0;                       // retire async16(t+1) -> publish ldsB[nbf]
    LGK0;                      // publish AWRITE ds_writes
    BAR;                       // single per-tile barrier
  }
#undef ASTAGE
#undef AWRITE
#undef BWISSUE
#undef RDA
#undef RDB
#undef MM
#undef SBAR
#undef VM4
#undef VM0
#undef LGK0
#undef BAR
#undef PRIO1
#undef PRIO0

  // ---- epilogue ----
  const int row0 = bm * 256 + wm * 128 + quad * 4;
  const int colT = bn * 256 + wn * 64 + m16;

  if (is0) {
    const float* bias = bias_proj;
    float p1[8][4] = {}, p2[8][4] = {};
    const bool haveHead = (bn == 0);
#pragma unroll
    for (int ai = 0; ai < 8; ++ai) {
#pragma unroll
      for (int j = 0; j < 4; ++j) {
        const int col = colT + j * 16;
        const float bcol = bias[col];
        float w1c = 0.f, w2c = 0.f;
        if (haveHead && col < 100) { w1c = w_head[col]; w2c = w_head[100 + col]; }
#pragma unroll
        for (int r = 0; r < 4; ++r) {
          const int row = row0 + ai * 16 + r;
          float v = fast_tanh(acc[ai][j][r] + bcol);
          if (col >= 100 && col < 500) out_label[(size_t)row * 400 + col - 100] = v;
          p1[ai][r] += v * w1c;
          p2[ai][r] += v * w2c;
        }
      }
    }
    if (haveHead) {
      if (wn < 2) {
#pragma unroll
        for (int d = 1; d < 16; d <<= 1)
#pragma unroll
          for (int ai = 0; ai < 8; ++ai)
#pragma unroll
            for (int r = 0; r < 4; ++r) {
              p1[ai][r] += __shfl_xor(p1[ai][r], d);
              p2[ai][r] += __shfl_xor(p2[ai][r], d);
            }
        if (m16 == 0) {
#pragma unroll
          for (int ai = 0; ai < 8; ++ai)
#pragma unroll
            for (int r = 0; r < 4; ++r) {
              int rl = wm * 128 + ai * 16 + quad * 4 + r;
              s1red[wn][rl] = p1[ai][r];
              s2red[wn][rl] = p2[ai][r];
            }
        }
      }
      __syncthreads();
      if (tid < 256) s1[bm * 256 + tid] = s1red[0][tid] + s1red[1][tid];
      else { int t2 = tid - 256; s2[bm * 256 + t2] = s2red[0][t2] + s2red[1][t2]; }
    }
  } else {
    const float* bias = bias_aux;
#pragma unroll
    for (int ai = 0; ai < 8; ++ai)
#pragma unroll
      for (int j = 0; j < 4; ++j) {
        const int col = colT + j * 16;
        if (col < 500) {
          const float bcol = bias[col];
#pragma unroll
          for (int r = 0; r < 4; ++r) {
            const int row = row0 + ai * 16 + r;
            aux_cat[(size_t)row * 640 + col] = f2h(fast_tanh(acc[ai][j][r] + bcol));
          }
        }
      }
    if (bn == 0) {                           // bny==2: lang/pad cols [500,640)
      for (int idx = tid; idx < 256 * 35; idx += 512) {
        int rr = idx / 35, qq = idx - rr * 35;
        int col = 500 + 4 * qq;
        f16x4 h = { (f16)0.f, (f16)0.f, (f16)0.f, (f16)0.f };
        if (col < 600) h = cvt4(*(const float4*)(lrow + col - 500));
        *(f16x4*)(aux_cat + (size_t)(bm * 256 + rr) * 640 + col) = h;
      }
    }
  }
}

// ---------------------------------------------------------------------------
// Fused GEMM2 + arcs, grid (64, 4), 512 threads, free-run 1-barrier/tile
// (unchanged from R5 -- this schedule is what made gemm2 fast):
//   heads GEMM A=aux_cat[16384,640] B=W_heads[1024,640] K=640 NT=10;
//   cols<20 upos | <320 xpos | <820 attrs. Then arcs rows [bm*256+bn*64,+64).
// ---------------------------------------------------------------------------
__global__ __launch_bounds__(512, 2) void gemm2_arcs(
    const f16* __restrict__ aux_cat, const f16* __restrict__ W_heads,
    const float* __restrict__ bias_heads,
    const float* __restrict__ s1, const float* __restrict__ s2,
    const float* __restrict__ b_head,
    float* __restrict__ out_arcs, float* __restrict__ out_upos,
    float* __restrict__ out_xpos, float* __restrict__ out_attrs)
{
  __shared__ __align__(16) f16 ldsA[2 * 16384];
  __shared__ __align__(16) f16 ldsB[2 * 16384];

  const int tid  = threadIdx.x;
  const int lane = tid & 63;
  const int wave = tid >> 6;
  const int wm = wave >> 2, wn = wave & 3;
  const int m16 = lane & 15, quad = lane >> 4;
  const int bm = blockIdx.x, bn = blockIdx.y;
  const int K = 640, NT = 10;

  const int sr = lane >> 3;
  const int ss = (lane & 7) ^ sr;
  const f16* gA[4]; const f16* gB[4];
#pragma unroll
  for (int i = 0; i < 4; ++i) {
    gA[i] = aux_cat + (size_t)(bm * 256 + i * 64 + wave * 8 + sr) * K + ss * 8;
    gB[i] = W_heads + (size_t)(bn * 256 + i * 64 + wave * 8 + sr) * K + ss * 8;
  }
  f16* sA = ldsA + wave * 512;
  f16* sB = ldsB + wave * 512;

  const int aBase = (wm * 128 + m16) * 64;
  const int bBase = (wn * 64  + m16) * 64;
  const int sw0 = ((quad)     ^ (m16 & 7)) * 8;
  const int sw1 = ((4 | quad) ^ (m16 & 7)) * 8;

  f32x4 acc[8][4] = {};
  f16x8 af[4], bf[4];

#define STAGE8(k0n, nbf) do {                                                   \
    async16(sA + (nbf) + 0 * 4096, gA[0] + (k0n));                              \
    async16(sA + (nbf) + 1 * 4096, gA[1] + (k0n));                              \
    async16(sA + (nbf) + 2 * 4096, gA[2] + (k0n));                              \
    async16(sA + (nbf) + 3 * 4096, gA[3] + (k0n));                              \
    async16(sB + (nbf) + 0 * 4096, gB[0] + (k0n));                              \
    async16(sB + (nbf) + 1 * 4096, gB[1] + (k0n));                              \
    async16(sB + (nbf) + 2 * 4096, gB[2] + (k0n));                              \
    async16(sB + (nbf) + 3 * 4096, gB[3] + (k0n)); } while (0)

#define RDA(mqv, sw) { _Pragma("unroll")                                        \
  for (int ii = 0; ii < 4; ++ii)                                                \
    af[ii] = *(const f16x8*)&ldsA[buf + aBase + (mqv) * 4096 + ii * 1024 + (sw)]; }
#define RDB(sw) { _Pragma("unroll")                                             \
  for (int j = 0; j < 4; ++j)                                                   \
    bf[j] = *(const f16x8*)&ldsB[buf + bBase + j * 1024 + (sw)]; }
#define MM(mqv) { _Pragma("unroll")                                             \
  for (int ii = 0; ii < 4; ++ii) { _Pragma("unroll")                            \
    for (int j = 0; j < 4; ++j)                                                 \
      acc[(mqv) * 4 + ii][j] = __builtin_amdgcn_mfma_f32_16x16x32_f16(          \
          af[ii], bf[j], acc[(mqv) * 4 + ii][j], 0, 0, 0); } }
#define VM0  asm volatile("s_waitcnt vmcnt(0)" ::: "memory")
#define BAR  __builtin_amdgcn_s_barrier()
#define PRIO1 __builtin_amdgcn_s_setprio(1)
#define PRIO0 __builtin_amdgcn_s_setprio(0)

  STAGE8(0, 0);
  VM0;
  BAR;

  for (int t = 0; t < NT; ++t) {
    const int buf = (t & 1) << 14;
    const int nbf = ((t + 1) & 1) << 14;
    const bool st = (t + 1 < NT);
    const int k0n = (t + 1) << 6;

    RDB(sw0); RDA(0, sw0);
    if (st) STAGE8(k0n, nbf);
    PRIO1; MM(0); PRIO0;
    RDA(1, sw0);
    PRIO1; MM(1); PRIO0;
    RDB(sw1); RDA(0, sw1);
    PRIO1; MM(0); PRIO0;
    RDA(1, sw1);
    PRIO1; MM(1); PRIO0;
    VM0;                      // retire async16(t+1) -> publish lds[nbf]
    BAR;                      // single per-tile barrier
  }
#undef STAGE8
#undef RDA
#undef RDB
#undef MM
#undef VM0
#undef BAR
#undef PRIO1
#undef PRIO0

  const int row0 = bm * 256 + wm * 128 + quad * 4;
  const int colT = bn * 256 + wn * 64 + m16;
#pragma unroll
  for (int ai = 0; ai < 8; ++ai)
#pragma unroll
    for (int j = 0; j < 4; ++j) {
      const int col = colT + j * 16;
      const float bcol = bias_heads[col];
#pragma unroll
      for (int r = 0; r < 4; ++r) {
        const int row = row0 + ai * 16 + r;
        float v = acc[ai][j][r] + bcol;
        if (col < 20)        out_upos[(size_t)row * 20 + col] = v;
        else if (col < 320)  out_xpos[(size_t)row * 300 + col - 20] = v;
        else if (col < 820)  out_attrs[(size_t)row * 500 + col - 320] = v;
      }
    }

  // ---- arcs: 64 rows per block, 512 threads = one full row per pass ----
  const int r0 = bm * 256 + bn * 64;
  const float bh = b_head[0];
  const float s2v = s2[((r0 >> 9) << 9) + tid];
  for (int rl = 0; rl < 64; ++rl) {
    const int row = r0 + rl;
    const float s1v = s1[row] + bh;
    float* orow = out_arcs + (size_t)row * 513;
    if (tid == 0) orow[0] = 0.f;
    orow[1 + tid] = s1v + s2v;
  }
}

// ---------------------------------------------------------------------------
extern "C" void kernel_launch(void* const* d_in, const int* in_sizes, int n_in,
                              void* d_out, int out_size, void* d_ws, size_t ws_size,
                              hipStream_t stream)
{
  const float* emb      = (const float*)d_in[0];   // [32,512,500]
  const float* hidden   = (const float*)d_in[1];   // [32,512,800]
  const int*   lang_ids = (const int*)d_in[2];     // [32]
  const float* lang_tab = (const float*)d_in[3];   // [8,100]
  const float* W_arc  = (const float*)d_in[4];
  const float* b_arc  = (const float*)d_in[5];
  const float* W_lab  = (const float*)d_in[6];
  const float* b_lab  = (const float*)d_in[7];
  const float* w_head = (const float*)d_in[8];
  const float* b_head = (const float*)d_in[9];
  const float* W_aux  = (const float*)d_in[10];
  const float* b_aux  = (const float*)d_in[11];
  const float* W_upos = (const float*)d_in[12];
  const float* b_upos = (const float*)d_in[13];
  const float* W_xpos = (const float*)d_in[14];
  const float* b_xpos = (const float*)d_in[15];
  const float* W_attrs = (const float*)d_in[16];
  const float* b_attrs = (const float*)d_in[17];

  char* ws = (char*)d_ws;
  f16* aux_cat = (f16*)(ws + 0);                  // 16384*640*2 = 20,971,520
  f16* W_proj  = (f16*)(ws + 20971520);           // 512*640*2   =    655,360
  f16* W_auxp  = (f16*)(ws + 21626880);           // 512*832*2   =    851,968
  f16* W_heads = (f16*)(ws + 22478848);           // 1024*640*2  =  1,310,720
  float* bias_proj  = (float*)(ws + 23789568);    // 512*4
  float* bias_aux   = (float*)(ws + 23791616);    // 512*4
  float* bias_heads = (float*)(ws + 23793664);    // 1024*4
  float* s1         = (float*)(ws + 23797760);    // 16384*4
  float* s2         = (float*)(ws + 23863296);    // 16384*4
  // total ws use: 23,928,832 bytes

  float* out       = (float*)d_out;
  float* out_arcs  = out;                 // 8,404,992
  float* out_label = out + 8404992;       // 6,553,600
  float* out_upos  = out + 14958592;      //   327,680
  float* out_xpos  = out + 15286272;      // 4,915,200
  float* out_attrs = out + 20201472;      // 8,192,000

  setup_kernel<<<1377, 256, 0, stream>>>(
      W_arc, b_arc, W_lab, b_lab, W_aux, b_aux,
      W_upos, b_upos, W_xpos, b_xpos, W_attrs, b_attrs,
      W_proj, W_auxp, W_heads, bias_proj, bias_aux, bias_heads);

  gemm01<<<dim3(64, 4), 512, 0, stream>>>(
      emb, hidden, lang_tab, lang_ids, W_proj, W_auxp, bias_proj, bias_aux,
      out_label, w_head, s1, s2, aux_cat);

  gemm2_arcs<<<dim3(64, 4), 512, 0, stream>>>(
      aux_cat, W_heads, bias_heads, s1, s2, b_head,
      out_arcs, out_upos, out_xpos, out_attrs);
}